// Round 7
// baseline (420.476 us; speedup 1.0000x reference)
//
#include <hip/hip_runtime.h>

// ---------------------------------------------------------------------------
// GALE_FA: FLARE low-rank self-attn + context cross-attn + gated mix.
// R4 collapse: logits computed directly from x (k/q never materialized).
// R5: k_L split into dec/cross kernels; R6: launch_bounds(256,3) reg cap
// (3 blocks/CU) on k_Ldec/k_Lcross + latT split-K 16.
// ---------------------------------------------------------------------------

typedef unsigned short u16;
typedef __attribute__((ext_vector_type(4))) float  f32x4;
typedef __attribute__((ext_vector_type(4))) u16    u16x4;
typedef __attribute__((ext_vector_type(8))) __bf16 bf16x8;

__device__ __forceinline__ float bf2f(u16 u) {
    return __uint_as_float(((unsigned)u) << 16);
}
__device__ __forceinline__ u16 f2bf(float f) {   // round-to-nearest-even
    unsigned u = __float_as_uint(f);
    u += 0x7fffu + ((u >> 16) & 1u);
    return (u16)(u >> 16);
}
__device__ __forceinline__ void gload16(const void* g, void* l) {
    __builtin_amdgcn_global_load_lds(
        (const __attribute__((address_space(1))) unsigned int*)g,
        (__attribute__((address_space(3))) unsigned int*)l, 16, 0, 0);
}

#define MASK_NONE 0x7fffffffu

// ---------------------------------------------------------------------------
// Generic MFMA GEMM core (m97-style 2-barrier loop, BK=32).
// ---------------------------------------------------------------------------
template<int BM, int BN, int WMW, int WNW>
__device__ __forceinline__ void gemm_core(
    const u16* __restrict__ A, int lda, unsigned amask, int koffA,
    const u16* __restrict__ Bm, int ldb, unsigned bmask, int koffB,
    int K, int trow, int tcol,
    u16* As, u16* Bs,
    f32x4 (&acc)[BM / WMW / 16][BN / WNW / 16])
{
    constexpr int FM = BM / WMW / 16;
    constexpr int FN = BN / WNW / 16;
    const int tid  = threadIdx.x;
    const int wid  = tid >> 6, lane = tid & 63;
    const int wm   = wid % WMW, wn = wid / WMW;
    const int wr   = wm * (BM / WMW), wc = wn * (BN / WNW);
    const int lrow = lane & 15, lk = (lane >> 4) * 8;

    for (int kt = 0; kt < K; kt += 32) {
        __syncthreads();
#pragma unroll
        for (int i = 0; i < BM / 64; i++) {           // stage A tile
            int c = i * 256 + tid;
            int row = c >> 2, kg = c & 3;
            unsigned kk = ((unsigned)(koffA + kt + kg * 8)) & amask;
            gload16(A + (size_t)(trow + row) * lda + kk, As + (size_t)c * 8);
        }
#pragma unroll
        for (int i = 0; i < BN / 64; i++) {           // stage B tile
            int c = i * 256 + tid;
            int col = c >> 2, kg = c & 3;
            unsigned kk = ((unsigned)(koffB + kt + kg * 8)) & bmask;
            gload16(Bm + (size_t)(tcol + col) * ldb + kk, Bs + (size_t)c * 8);
        }
        __syncthreads();

        bf16x8 af[FM], bfr[FN];
#pragma unroll
        for (int fm = 0; fm < FM; fm++)
            af[fm] = *(const bf16x8*)&As[(wr + fm * 16 + lrow) * 32 + lk];
#pragma unroll
        for (int fn = 0; fn < FN; fn++)
            bfr[fn] = *(const bf16x8*)&Bs[(wc + fn * 16 + lrow) * 32 + lk];
#pragma unroll
        for (int fm = 0; fm < FM; fm++)
#pragma unroll
            for (int fn = 0; fn < FN; fn++)
                acc[fm][fn] = __builtin_amdgcn_mfma_f32_16x16x32_bf16(
                    af[fm], bfr[fn], acc[fm][fn], 0, 0, 0);
    }
}

// ---------------------------------------------------------------------------
// Prep kernels (fp32 inputs)
// ---------------------------------------------------------------------------

// x -> xs = [xh | xl] bf16 per row (row stride 1024)
__global__ void prep_x(const float* __restrict__ x, u16* __restrict__ xs)
{
    int t = blockIdx.x * 256 + threadIdx.x;       // 2*16384*512/4
    int n = t >> 7, e4 = (t & 127) << 2;
    f32x4 v = *(const f32x4*)(x + (size_t)n * 512 + e4);
    u16x4 hi, lo;
#pragma unroll
    for (int j = 0; j < 4; j++) {
        u16 h = f2bf(v[j]);
        hi[j] = h;
        lo[j] = f2bf(v[j] - bf2f(h));
    }
    *(u16x4*)(xs + (size_t)n * 1024 + e4)       = hi;
    *(u16x4*)(xs + (size_t)n * 1024 + 512 + e4) = lo;
}

// which 0/1/2: CKF/CQF fp32, wV bf16 (composed with Wx); which 3: Wo -> bf16.
__global__ void prep_w(const float* Wk, const float* Wcq, const float* Wv,
                       const float* Wx, const float* Wo,
                       float* CKF, float* CQF, u16* wV, u16* wo16)
{
    int idx = blockIdx.x * 256 + threadIdx.x;     // 4*512*512
    int which = idx >> 18;
    int rem = idx & 262143;
    if (which == 3) { wo16[rem] = f2bf(Wo[rem]); return; }
    int c = rem >> 9, e = rem & 511;
    int h = c >> 6, d = c & 63;
    const float* W = which == 0 ? Wk : (which == 1 ? Wcq : Wv);
    float s = 0.f;
#pragma unroll 8
    for (int j = 0; j < 64; j++)
        s += W[d * 64 + j] * Wx[(h * 64 + j) * 512 + e];
    if (which == 0)      CKF[(size_t)c * 512 + e] = s;
    else if (which == 1) CQF[(size_t)c * 512 + e] = s;
    else                 wV [(size_t)c * 512 + e] = f2bf(s);
}

// Composed biases: biasKQ[0..511]=k-bias(h,d), [512..1023]=q-bias; biasV.
__global__ void prep_bias(const float* Wk, const float* Wcq, const float* Wv,
                          const float* bk, const float* bcq, const float* bv,
                          const float* bx, float* biasKQ, float* biasV)
{
    int t = blockIdx.x * 256 + threadIdx.x;       // 1536
    if (t < 1024) {
        const float* W  = (t < 512) ? Wk : Wcq;
        const float* bb = (t < 512) ? bk : bcq;
        int c = t & 511; int h = c >> 6, d = c & 63;
        float s = bb[d];
        for (int j = 0; j < 64; j++) s += W[d * 64 + j] * bx[h * 64 + j];
        biasKQ[t] = s;
    } else if (t < 1536) {
        int c = t - 1024; int h = c >> 6, d = c & 63;
        float s = bv[d];
        for (int j = 0; j < 64; j++) s += Wv[d * 64 + j] * bx[h * 64 + j];
        biasV[c] = s;
    }
}

// context: kc fp32 [bh][s][d]; vcT bf16 [bh][d][s] pre-scaled by (1-sigmoid(smix)).
__global__ void prep_ctx(const float* ctx, const float* Wck, const float* bck,
                         const float* Wcv, const float* bcv, const float* smix,
                         float* kcf, u16* vcT)
{
    int t = blockIdx.x * 256 + threadIdx.x;       // 16*64*64
    int bh = t >> 12, r = t & 4095;
    int s_ = r >> 6, d = r & 63;
    const float* crow = ctx + ((size_t)bh * 64 + s_) * 64;
    float kc = bck[d], vc = bcv[d];
#pragma unroll 8
    for (int e = 0; e < 64; e++) {
        float ce = crow[e];
        kc += ce * Wck[d * 64 + e];
        vc += ce * Wcv[d * 64 + e];
    }
    kcf[(size_t)bh * 4096 + s_ * 64 + d] = kc;
    float w = 1.f / (1.f + __expf(-smix[0]));
    vcT[(size_t)bh * 4096 + d * 64 + s_] = f2bf((1.f - w) * vc);
}

// Merged: kg rows (BigB 0..511, both b), kq rows (BigB 512+hs), CC consts.
__global__ void prep_b2(const float* CKF, const float* CQF, const float* qg,
                        const float* kcf, const float* biasKQ, u16* BigB, float* CC)
{
    int idx = blockIdx.x * 256 + threadIdx.x;     // 262144 + 524288 + 1536
    if (idx < 262144) {
        int hm = idx >> 9, e = idx & 511;
        int h = hm >> 6;
        float s = 0.f;
#pragma unroll 8
        for (int d = 0; d < 64; d++)
            s += CKF[(size_t)(h * 64 + d) * 512 + e] * qg[(size_t)hm * 64 + d];
        u16 hi = f2bf(s), lo = f2bf(s - bf2f(hi));
#pragma unroll
        for (int b = 0; b < 2; b++) {
            size_t base = (size_t)b * 1572864 + (size_t)hm * 1536;
            BigB[base + e]        = lo;
            BigB[base + 512 + e]  = hi;
            BigB[base + 1024 + e] = hi;
        }
    } else if (idx < 786432) {
        int i2 = idx - 262144;
        int r = i2 >> 9, e = i2 & 511;
        int b = r >> 9, hs = r & 511;
        int h = hs >> 6, s_ = hs & 63;
        float s = 0.f;
#pragma unroll 8
        for (int d = 0; d < 64; d++)
            s += CQF[(size_t)(h * 64 + d) * 512 + e]
               * kcf[(size_t)(b * 8 + h) * 4096 + s_ * 64 + d];
        u16 hi = f2bf(s), lo = f2bf(s - bf2f(hi));
        size_t base = (size_t)b * 1572864 + (size_t)(512 + hs) * 1536;
        BigB[base + e]        = lo;
        BigB[base + 512 + e]  = hi;
        BigB[base + 1024 + e] = hi;
    } else if (idx < 787968) {
        int t = idx - 786432;                     // 0..1535
        if (t < 512) {
            int h = t >> 6;
            float s = 0.f;
            for (int d = 0; d < 64; d++) s += biasKQ[h * 64 + d] * qg[(size_t)t * 64 + d];
            CC[t] = s; CC[1024 + t] = s;
        } else {
            int j = t - 512;
            int b = j >> 9, hs = j & 511;
            int h = hs >> 6, s_ = hs & 63;
            float s = 0.f;
            for (int d = 0; d < 64; d++)
                s += biasKQ[512 + h * 64 + d]
                   * kcf[(size_t)(b * 8 + h) * 4096 + s_ * 64 + d];
            CC[b * 1024 + 512 + hs] = s;
        }
    }
}

// vT = CV @ xh^T (+row bias): vT[b][hd][n]  (xh = hi half of xs, bmask=511)
__global__ __launch_bounds__(256, 2) void k_vt(const u16* wV, const u16* xs,
                                               const float* biasV, u16* vT)
{
    __shared__ u16 As[128 * 32], Bs[128 * 32];
    f32x4 acc[4][4] = {};
    int b = blockIdx.z;
    int f = blockIdx.y * gridDim.x + blockIdx.x;       // 512 blocks per z
    int w = (f & 7) * 64 + (f >> 3);
    int trow = (w & 3) * 128;
    int tcol = (w >> 2) * 128;
    gemm_core<128, 128, 2, 2>(wV, 512, MASK_NONE, 0,
                              xs + (size_t)b * 16777216, 1024, 511u, 0,
                              512, trow, tcol, As, Bs, acc);
    int tid = threadIdx.x, wid = tid >> 6, lane = tid & 63;
    int wr = (wid & 1) * 64, wc = (wid >> 1) * 64;
    int g = lane >> 4, li = lane & 15;
#pragma unroll
    for (int fm = 0; fm < 4; fm++)
#pragma unroll
        for (int fn = 0; fn < 4; fn++) {
            int col = tcol + wc + fn * 16 + li;
#pragma unroll
            for (int j = 0; j < 4; j++) {
                int a = trow + wr + fm * 16 + g * 4 + j;
                vT[((size_t)b * 512 + a) * 16384 + col] = f2bf(acc[fm][fn][j] + biasV[a]);
            }
        }
}

// ---------------------------------------------------------------------------
// k_Ldec: dec/enc logit cols (0..511). 128n x 128(h,m) per block.
// E=exp(L+c1); dec-softmax over m -> P1n; den_enc partials; den_dec -> DD.
// launch_bounds(256,3): cap 170 regs/wave -> 3 blocks/CU.
// ---------------------------------------------------------------------------
__global__ __launch_bounds__(256, 3) void k_Ldec(const u16* xs, const u16* BigB,
                                                 const float* CC,
                                                 u16* P1n, float* DD, float* denp)
{
    __shared__ u16 As[128 * 32], Bs[128 * 32];
    f32x4 acc[4][4] = {};
    int f = blockIdx.x;                  // 1024
    int w = (f & 7) * 128 + (f >> 3);    // XCD-chunked, bijective
    int jt = w & 3, nb = w >> 2;
    int b = nb >> 7, ntile = nb & 127;
    int trow = ntile * 128, tcol = jt * 128;
    gemm_core<128, 128, 2, 2>(xs + (size_t)b * 16777216, 1024, 1023u, 0,
                              BigB + (size_t)b * 1572864, 1536, MASK_NONE, 0,
                              1536, trow, tcol, As, Bs, acc);
    int tid = threadIdx.x, wid = tid >> 6, lane = tid & 63;
    int wm = wid & 1, wn = wid >> 1;
    int wr = wm * 64, wc = wn * 64;
    int g = lane >> 4, li = lane & 15;
    float cj[4];
#pragma unroll
    for (int fn = 0; fn < 4; fn++) cj[fn] = CC[b * 1024 + tcol + wc + fn * 16 + li];

    int h = jt * 2 + wn;
    float colsum[4] = {0.f, 0.f, 0.f, 0.f};
#pragma unroll
    for (int fm = 0; fm < 4; fm++)
#pragma unroll
        for (int j = 0; j < 4; j++) {
            float ev[4]; float dsum = 0.f;
#pragma unroll
            for (int fn = 0; fn < 4; fn++) {
                ev[fn] = __expf(acc[fm][fn][j] + cj[fn]);
                dsum += ev[fn];
                colsum[fn] += ev[fn];
            }
            dsum += __shfl_xor(dsum, 1); dsum += __shfl_xor(dsum, 2);
            dsum += __shfl_xor(dsum, 4); dsum += __shfl_xor(dsum, 8);
            float inv = 1.f / dsum;
            int row = trow + wr + fm * 16 + g * 4 + j;
            size_t pb = ((size_t)b * 16384 + row) * 512 + h * 64;
#pragma unroll
            for (int fn = 0; fn < 4; fn++)
                P1n[pb + fn * 16 + li] = f2bf(ev[fn] * inv);
            if (li == 0) DD[(size_t)(b * 8 + h) * 16384 + row] = dsum;
        }
#pragma unroll
    for (int fn = 0; fn < 4; fn++) {
        float cs = colsum[fn];
        cs += __shfl_xor(cs, 16); cs += __shfl_xor(cs, 32);
        if (lane < 16)
            denp[(size_t)(b * 512 + h * 64 + fn * 16 + li) * 256 + ntile * 2 + wm] = cs;
    }
}

// ---------------------------------------------------------------------------
// k_Lcross: cross logit cols (512..1023). softmax over s -> P2 (LDS, aliases
// As/Bs) -> PV2 vs vcT (B-fragments direct from global, L2-resident) -> OM2.
// ---------------------------------------------------------------------------
__global__ __launch_bounds__(256, 3) void k_Lcross(const u16* xs, const u16* BigB,
                                                   const float* CC, const u16* vcT,
                                                   u16* OM2)
{
    __shared__ u16 sh[8192];             // As | Bs ; P2L aliases all 16KB
    u16* As = sh; u16* Bs = sh + 4096;
    u16* P2L = sh;                       // 128 x 64 u16, XOR-swizzled
    f32x4 acc[4][4] = {};
    int f = blockIdx.x;                  // 1024
    int w = (f & 7) * 128 + (f >> 3);
    int jt = w & 3, nb = w >> 2;
    int b = nb >> 7, ntile = nb & 127;
    int trow = ntile * 128, tcol = 512 + jt * 128;
    gemm_core<128, 128, 2, 2>(xs + (size_t)b * 16777216, 1024, 1023u, 0,
                              BigB + (size_t)b * 1572864, 1536, MASK_NONE, 0,
                              1536, trow, tcol, As, Bs, acc);
    int tid = threadIdx.x, wid = tid >> 6, lane = tid & 63;
    int wm = wid & 1, wn = wid >> 1;
    int wr = wm * 64, wc = wn * 64;
    int g = lane >> 4, li = lane & 15;
    int lrow = lane & 15, lk = g * 8;
    float cj[4];
#pragma unroll
    for (int fn = 0; fn < 4; fn++) cj[fn] = CC[b * 1024 + tcol + wc + fn * 16 + li];

    int hpair = jt * 2;
    for (int hh = 0; hh < 2; hh++) {
        __syncthreads();                 // LDS (As/Bs or prev P2L) safe to reuse
        int h2 = hpair + hh;
        const u16* vcg = vcT + (size_t)(b * 8 + h2) * 4096;
        if (wn == hh) {                  // this wave-pair's cols = head h2
#pragma unroll
            for (int fm = 0; fm < 4; fm++)
#pragma unroll
                for (int j = 0; j < 4; j++) {
                    float ev[4]; float ssum = 0.f;
#pragma unroll
                    for (int fn = 0; fn < 4; fn++) {
                        ev[fn] = __expf(acc[fm][fn][j] + cj[fn]);
                        ssum += ev[fn];
                    }
                    ssum += __shfl_xor(ssum, 1); ssum += __shfl_xor(ssum, 2);
                    ssum += __shfl_xor(ssum, 4); ssum += __shfl_xor(ssum, 8);
                    float inv = 1.f / ssum;
                    int rl = wr + fm * 16 + g * 4 + j;
#pragma unroll
                    for (int fn = 0; fn < 4; fn++) {
                        int s = fn * 16 + li;
                        P2L[rl * 64 + (s ^ ((rl & 7) << 3))] = f2bf(ev[fn] * inv);
                    }
                }
        }
        __syncthreads();
        // PV2: out2[n][d] = sum_s P2[n][s] * vcT[d][s]
        f32x4 oacc[2][4] = {};
#pragma unroll
        for (int kt = 0; kt < 64; kt += 32) {
            bf16x8 paf[2], vbf[4];
#pragma unroll
            for (int fm = 0; fm < 2; fm++) {
                int r = wid * 32 + fm * 16 + lrow;
                paf[fm] = *(const bf16x8*)&P2L[r * 64 + ((kt + lk) ^ ((r & 7) << 3))];
            }
#pragma unroll
            for (int fn = 0; fn < 4; fn++) {
                int d2 = fn * 16 + lrow;
                vbf[fn] = *(const bf16x8*)&vcg[d2 * 64 + kt + lk];
            }
#pragma unroll
            for (int fm = 0; fm < 2; fm++)
#pragma unroll
                for (int fn = 0; fn < 4; fn++)
                    oacc[fm][fn] = __builtin_amdgcn_mfma_f32_16x16x32_bf16(
                        paf[fm], vbf[fn], oacc[fm][fn], 0, 0, 0);
        }
#pragma unroll
        for (int fm = 0; fm < 2; fm++)
#pragma unroll
            for (int fn = 0; fn < 4; fn++)
#pragma unroll
                for (int j = 0; j < 4; j++) {
                    int rl = wid * 32 + fm * 16 + g * 4 + j;
                    OM2[((size_t)b * 16384 + trow + rl) * 512 + h2 * 64 + fn * 16 + li]
                        = f2bf(oacc[fm][fn][j]);
                }
    }
}

// ---------------------------------------------------------------------------
// latT: latp[ch][bh][d][m] = sum_n vT[d][n] * (P1n[n][h,m]*DD[n])  (split-K 16)
// ---------------------------------------------------------------------------
__global__ __launch_bounds__(256, 2) void k_latT(const u16* vT, const u16* P1n,
                                                 const float* DD, float* latp)
{
    __shared__ u16 As[64 * 32], Bs[64 * 32];
    f32x4 acc[2][2] = {};
    int ch = blockIdx.x, bh = blockIdx.z;
    int b = bh >> 3, h = bh & 7;
    int koff = ch * 1024;
    int tid = threadIdx.x, wid = tid >> 6, lane = tid & 63;
    int wr = (wid & 1) * 32, wc = (wid >> 1) * 32;
    int lrow = lane & 15, lk = (lane >> 4) * 8;
    const u16* Avt = vT + (size_t)bh * 64 * 16384;

    for (int kt = 0; kt < 1024; kt += 32) {
        __syncthreads();
        {   // stage A: vT rows 64 x 32k
            int row = tid >> 2, kg = tid & 3;
            gload16(Avt + (size_t)row * 16384 + koff + kt + kg * 8, As + (size_t)tid * 8);
        }
        {   // stage B transposed: Bs[m][n], XOR-swizzled (n ^ ((m&3)<<3))
            int nl = tid & 31, m0 = (tid >> 5) * 8;
            int n = koff + kt + nl;
            const u16* src = P1n + ((size_t)b * 16384 + n) * 512 + h * 64 + m0;
            u16x4 p0 = *(const u16x4*)src;
            u16x4 p1 = *(const u16x4*)(src + 4);
            float ddv = DD[(size_t)bh * 16384 + n];
#pragma unroll
            for (int i = 0; i < 4; i++) {
                int m = m0 + i;
                Bs[m * 32 + (nl ^ ((m & 3) << 3))] = f2bf(bf2f(p0[i]) * ddv);
            }
#pragma unroll
            for (int i = 0; i < 4; i++) {
                int m = m0 + 4 + i;
                Bs[m * 32 + (nl ^ ((m & 3) << 3))] = f2bf(bf2f(p1[i]) * ddv);
            }
        }
        __syncthreads();
        bf16x8 af[2], bfv[2];
#pragma unroll
        for (int fm = 0; fm < 2; fm++)
            af[fm] = *(const bf16x8*)&As[(wr + fm * 16 + lrow) * 32 + lk];
#pragma unroll
        for (int fn = 0; fn < 2; fn++) {
            int m = wc + fn * 16 + lrow;
            bfv[fn] = *(const bf16x8*)&Bs[m * 32 + (lk ^ ((m & 3) << 3))];
        }
#pragma unroll
        for (int fm = 0; fm < 2; fm++)
#pragma unroll
            for (int fn = 0; fn < 2; fn++)
                acc[fm][fn] = __builtin_amdgcn_mfma_f32_16x16x32_bf16(
                    af[fm], bfv[fn], acc[fm][fn], 0, 0, 0);
    }
    float* C = latp + ((size_t)ch * 16 + bh) * 4096;
    int g = lane >> 4, li = lane & 15;
#pragma unroll
    for (int fm = 0; fm < 2; fm++)
#pragma unroll
        for (int fn = 0; fn < 2; fn++)
#pragma unroll
            for (int j = 0; j < 4; j++) {
                int row = wr + fm * 16 + g * 4 + j;   // d
                int col = wc + fn * 16 + li;          // m
                C[row * 64 + col] = acc[fm][fn][j];
            }
}

__global__ void k_rden(const float* denp, float* dene)
{
    int t = blockIdx.x * 256 + threadIdx.x;       // 1024
    if (t < 1024) {
        float s = 0.f;
        const float* p = denp + (size_t)t * 256;
        for (int i = 0; i < 256; i++) s += p[i];
        dene[t] = s;
    }
}

// finish latent: latB[bh][d][m] = w * (sum_ch latp)/den_enc[m]
__global__ void k_latfin(const float* latp, const float* dene, const float* smix,
                         u16* latB)
{
    int t = blockIdx.x * 256 + threadIdx.x;       // 16*64*64
    int bh = t >> 12, r = t & 4095;
    int m = r & 63;
    float w = 1.f / (1.f + __expf(-smix[0]));
    float s = 0.f;
    for (int c = 0; c < 16; c++) s += latp[((size_t)c * 16 + bh) * 4096 + r];
    int b = bh >> 3, h = bh & 7;
    float lat = s / dene[b * 512 + h * 64 + m];
    latB[(size_t)bh * 4096 + r] = f2bf(w * lat);
}

// ---------------------------------------------------------------------------
// k_om: OM[n][h*64+d] = sum_m P1n[n][h,m] * latB[bh][d][m] + OM2[n][h*64+d]
// ---------------------------------------------------------------------------
__global__ __launch_bounds__(256, 2) void k_om(const u16* P1n, const u16* latB,
                                               const u16* OM2, u16* OM)
{
    __shared__ u16 As[128 * 64], Bs2[64 * 64];
    int b = blockIdx.z, ntile = blockIdx.x;
    int tid = threadIdx.x, wid = tid >> 6, lane = tid & 63;
    int g = lane >> 4, li = lane & 15;
    int lrow = lane & 15, lk = g * 8;
    for (int h = 0; h < 8; h++) {
        __syncthreads();
#pragma unroll
        for (int i = 0; i < 4; i++) {     // stage A 128n x 64m swizzled
            int c = i * 256 + tid;
            int n = c >> 3, m0 = (c & 7) * 8;
            gload16(P1n + ((size_t)b * 16384 + ntile * 128 + n) * 512 + h * 64
                         + (m0 ^ ((n & 7) << 3)), As + (size_t)c * 8);
        }
#pragma unroll
        for (int i = 0; i < 2; i++) {     // stage B 64d x 64m swizzled
            int c = i * 256 + tid;
            int d = c >> 3, m0 = (c & 7) * 8;
            gload16(latB + (size_t)(b * 8 + h) * 4096 + d * 64
                         + (m0 ^ ((d & 7) << 3)), Bs2 + (size_t)c * 8);
        }
        __syncthreads();
        f32x4 oacc[2][4] = {};
#pragma unroll
        for (int kt = 0; kt < 64; kt += 32) {
            bf16x8 af[2], bfv[4];
#pragma unroll
            for (int fm = 0; fm < 2; fm++) {
                int r = wid * 32 + fm * 16 + lrow;
                af[fm] = *(const bf16x8*)&As[r * 64 + ((kt + lk) ^ ((r & 7) << 3))];
            }
#pragma unroll
            for (int fn = 0; fn < 4; fn++) {
                int d = fn * 16 + lrow;
                bfv[fn] = *(const bf16x8*)&Bs2[d * 64 + ((kt + lk) ^ ((d & 7) << 3))];
            }
#pragma unroll
            for (int fm = 0; fm < 2; fm++)
#pragma unroll
                for (int fn = 0; fn < 4; fn++)
                    oacc[fm][fn] = __builtin_amdgcn_mfma_f32_16x16x32_bf16(
                        af[fm], bfv[fn], oacc[fm][fn], 0, 0, 0);
        }
#pragma unroll
        for (int fm = 0; fm < 2; fm++)
#pragma unroll
            for (int fn = 0; fn < 4; fn++)
#pragma unroll
                for (int j = 0; j < 4; j++) {
                    int rl = wid * 32 + fm * 16 + g * 4 + j;
                    size_t addr = ((size_t)b * 16384 + ntile * 128 + rl) * 512
                                  + h * 64 + fn * 16 + li;
                    OM[addr] = f2bf(oacc[fm][fn][j] + bf2f(OM2[addr]));
                }
    }
}

// final: out(fp32) = OM @ Wo^T + bo.
__global__ __launch_bounds__(256, 2) void k_f(const u16* OM, const u16* wo16,
                                              const float* bo, float* out)
{
    __shared__ u16 As[128 * 32], Bs[128 * 32];
    f32x4 acc[4][4] = {};
    int f = blockIdx.y * gridDim.x + blockIdx.x;       // 1024 blocks
    int w = (f & 7) * 128 + (f >> 3);
    int tcol = (w & 3) * 128, trow = (w >> 2) * 128;
    gemm_core<128, 128, 2, 2>(OM, 512, MASK_NONE, 0, wo16, 512, MASK_NONE, 0,
                              512, trow, tcol, As, Bs, acc);
    int tid = threadIdx.x, wid = tid >> 6, lane = tid & 63;
    int wr = (wid & 1) * 64, wc = (wid >> 1) * 64;
    int g = lane >> 4, li = lane & 15;
#pragma unroll
    for (int fm = 0; fm < 4; fm++)
#pragma unroll
        for (int fn = 0; fn < 4; fn++) {
            int col = tcol + wc + fn * 16 + li;
            float bias = bo[col];
#pragma unroll
            for (int j = 0; j < 4; j++) {
                int row = trow + wr + fm * 16 + g * 4 + j;
                out[(size_t)row * 512 + col] = acc[fm][fn][j] + bias;
            }
        }
}

// ---------------------------------------------------------------------------
// Workspace layout (bytes), end ~184 MB (< proven-safe 209.7 MB).
// OM aliases XS (xs dead after k_Ldec/k_Lcross; k_om runs after).
// ---------------------------------------------------------------------------
static const size_t XS_OFF   = 0;            // u16 32768x1024   (67,108,864)
static const size_t OMB_OFF  = 0;            // u16 32768x512    (alias XS)
static const size_t P1N_OFF  = 67108864;     // u16 2x16384x512  (33,554,432)
static const size_t OM2_OFF  = 100663296;    // u16 2x16384x512  (33,554,432)
static const size_t VT_OFF   = 134217728;    // u16 2x512x16384  (33,554,432)
static const size_t CKF_OFF  = 167772160;    // f32 512x512      (1,048,576)
static const size_t CQF_OFF  = 168820736;    // f32 512x512      (1,048,576)
static const size_t WV_OFF   = 169869312;    // u16 512x512      (524,288)
static const size_t WO_OFF   = 170393600;    // u16 512x512      (524,288)
static const size_t BIGB_OFF = 170917888;    // u16 2x1024x1536  (6,291,456)
static const size_t KCF_OFF  = 177209344;    // f32 16x64x64     (262,144)
static const size_t VCT_OFF  = 177471488;    // u16 16x64x64     (131,072)
static const size_t BKQ_OFF  = 177602560;    // f32 1024         (4,096)
static const size_t BV_OFF   = 177606656;    // f32 512          (2,048)
static const size_t CC_OFF   = 177608704;    // f32 2048         (8,192)
static const size_t DENP_OFF = 177616896;    // f32 1024x256     (1,048,576)
static const size_t DENE_OFF = 178665472;    // f32 1024         (4,096)
static const size_t DD_OFF   = 178669568;    // f32 16x16384     (1,048,576)
static const size_t LATP_OFF = 179718144;    // f32 16x16x64x64  (4,194,304)
static const size_t LATB_OFF = 183912448;    // u16 16x64x64     (131,072)
// end: 184,043,520

extern "C" void kernel_launch(void* const* d_in, const int* in_sizes, int n_in,
                              void* d_out, int out_size, void* d_ws, size_t ws_size,
                              hipStream_t stream)
{
    const float* x    = (const float*)d_in[0];
    const float* ctx  = (const float*)d_in[1];
    const float* qg   = (const float*)d_in[2];
    const float* Wx   = (const float*)d_in[3];
    const float* bx   = (const float*)d_in[4];
    const float* Wk   = (const float*)d_in[5];
    const float* bk   = (const float*)d_in[6];
    const float* Wv   = (const float*)d_in[7];
    const float* bv   = (const float*)d_in[8];
    const float* Wcq  = (const float*)d_in[9];
    const float* bcq  = (const float*)d_in[10];
    const float* Wck  = (const float*)d_in[11];
    const float* bck  = (const float*)d_in[12];
    const float* Wcv  = (const float*)d_in[13];
    const float* bcv  = (const float*)d_in[14];
    const float* smix = (const float*)d_in[15];
    const float* Wo   = (const float*)d_in[16];
    const float* bo   = (const float*)d_in[17];

    char* ws = (char*)d_ws;
    u16*   xs    = (u16*)  (ws + XS_OFF);
    u16*   OM    = (u16*)  (ws + OMB_OFF);
    u16*   P1n   = (u16*)  (ws + P1N_OFF);
    u16*   OM2   = (u16*)  (ws + OM2_OFF);
    u16*   vT    = (u16*)  (ws + VT_OFF);
    float* CKF   = (float*)(ws + CKF_OFF);
    float* CQF   = (float*)(ws + CQF_OFF);
    u16*   wV    = (u16*)  (ws + WV_OFF);
    u16*   wo16  = (u16*)  (ws + WO_OFF);
    u16*   BigB  = (u16*)  (ws + BIGB_OFF);
    float* kcf   = (float*)(ws + KCF_OFF);
    u16*   vcT   = (u16*)  (ws + VCT_OFF);
    float* biasKQ= (float*)(ws + BKQ_OFF);
    float* biasV = (float*)(ws + BV_OFF);
    float* CC    = (float*)(ws + CC_OFF);
    float* denp  = (float*)(ws + DENP_OFF);
    float* dene  = (float*)(ws + DENE_OFF);
    float* DD    = (float*)(ws + DD_OFF);
    float* latp  = (float*)(ws + LATP_OFF);
    u16*   latB  = (u16*)  (ws + LATB_OFF);

    prep_w   <<< 4096, 256, 0, stream>>>(Wk, Wcq, Wv, Wx, Wo, CKF, CQF, wV, wo16);
    prep_bias<<<    6, 256, 0, stream>>>(Wk, Wcq, Wv, bk, bcq, bv, bx, biasKQ, biasV);
    prep_ctx <<<  256, 256, 0, stream>>>(ctx, Wck, bck, Wcv, bcv, smix, kcf, vcT);
    prep_x   <<<16384, 256, 0, stream>>>(x, xs);
    prep_b2  <<< 3078, 256, 0, stream>>>(CKF, CQF, qg, kcf, biasKQ, BigB, CC);

    k_vt    <<<dim3(128,   4, 2), 256, 0, stream>>>(wV, xs, biasV, vT);
    k_Ldec  <<<1024, 256, 0, stream>>>(xs, BigB, CC, P1n, DD, denp);
    k_Lcross<<<1024, 256, 0, stream>>>(xs, BigB, CC, vcT, OM2);
    k_latT  <<<dim3( 16,   1, 16), 256, 0, stream>>>(vT, P1n, DD, latp);
    k_rden  <<<    4, 256, 0, stream>>>(denp, dene);
    k_latfin<<<  256, 256, 0, stream>>>(latp, dene, smix, latB);
    k_om    <<<dim3(128,   1, 2), 256, 0, stream>>>(P1n, latB, OM2, OM);
    k_f     <<<dim3(  4, 256, 1), 256, 0, stream>>>(OM, wo16, bo, (float*)d_out);
}

// Round 8
// 400.193 us; speedup vs baseline: 1.0507x; 1.0507x over previous
//
#include <hip/hip_runtime.h>

// ---------------------------------------------------------------------------
// GALE_FA: FLARE low-rank self-attn + context cross-attn + gated mix.
// R4: logits computed directly from x (k/q never materialized).
// R7: k_Ldec/k_Lcross restructured to 128x64 tiles, 4 waves x (32r x 64c),
// acc[2][4] (32 regs) -> ~50% occupancy naturally, NO launch_bounds caps.
// ---------------------------------------------------------------------------

typedef unsigned short u16;
typedef __attribute__((ext_vector_type(4))) float  f32x4;
typedef __attribute__((ext_vector_type(4))) u16    u16x4;
typedef __attribute__((ext_vector_type(8))) __bf16 bf16x8;

__device__ __forceinline__ float bf2f(u16 u) {
    return __uint_as_float(((unsigned)u) << 16);
}
__device__ __forceinline__ u16 f2bf(float f) {   // round-to-nearest-even
    unsigned u = __float_as_uint(f);
    u += 0x7fffu + ((u >> 16) & 1u);
    return (u16)(u >> 16);
}
__device__ __forceinline__ void gload16(const void* g, void* l) {
    __builtin_amdgcn_global_load_lds(
        (const __attribute__((address_space(1))) unsigned int*)g,
        (__attribute__((address_space(3))) unsigned int*)l, 16, 0, 0);
}

#define MASK_NONE 0x7fffffffu

// ---------------------------------------------------------------------------
// Generic MFMA GEMM core (m97-style 2-barrier loop, BK=32), 256 threads.
// ---------------------------------------------------------------------------
template<int BM, int BN, int WMW, int WNW>
__device__ __forceinline__ void gemm_core(
    const u16* __restrict__ A, int lda, unsigned amask, int koffA,
    const u16* __restrict__ Bm, int ldb, unsigned bmask, int koffB,
    int K, int trow, int tcol,
    u16* As, u16* Bs,
    f32x4 (&acc)[BM / WMW / 16][BN / WNW / 16])
{
    constexpr int FM = BM / WMW / 16;
    constexpr int FN = BN / WNW / 16;
    const int tid  = threadIdx.x;
    const int wid  = tid >> 6, lane = tid & 63;
    const int wm   = wid % WMW, wn = wid / WMW;
    const int wr   = wm * (BM / WMW), wc = wn * (BN / WNW);
    const int lrow = lane & 15, lk = (lane >> 4) * 8;

    for (int kt = 0; kt < K; kt += 32) {
        __syncthreads();
#pragma unroll
        for (int i = 0; i < BM / 64; i++) {           // stage A tile
            int c = i * 256 + tid;
            int row = c >> 2, kg = c & 3;
            unsigned kk = ((unsigned)(koffA + kt + kg * 8)) & amask;
            gload16(A + (size_t)(trow + row) * lda + kk, As + (size_t)c * 8);
        }
#pragma unroll
        for (int i = 0; i < (BN >= 64 ? BN / 64 : 1); i++) {  // stage B tile
            int c = i * 256 + tid;
            if (BN >= 64 || c < BN * 4) {
                int col = c >> 2, kg = c & 3;
                unsigned kk = ((unsigned)(koffB + kt + kg * 8)) & bmask;
                gload16(Bm + (size_t)(tcol + col) * ldb + kk, Bs + (size_t)c * 8);
            }
        }
        __syncthreads();

        bf16x8 af[FM], bfr[FN];
#pragma unroll
        for (int fm = 0; fm < FM; fm++)
            af[fm] = *(const bf16x8*)&As[(wr + fm * 16 + lrow) * 32 + lk];
#pragma unroll
        for (int fn = 0; fn < FN; fn++)
            bfr[fn] = *(const bf16x8*)&Bs[(wc + fn * 16 + lrow) * 32 + lk];
#pragma unroll
        for (int fm = 0; fm < FM; fm++)
#pragma unroll
            for (int fn = 0; fn < FN; fn++)
                acc[fm][fn] = __builtin_amdgcn_mfma_f32_16x16x32_bf16(
                    af[fm], bfr[fn], acc[fm][fn], 0, 0, 0);
    }
}

// ---------------------------------------------------------------------------
// Prep kernels (fp32 inputs)
// ---------------------------------------------------------------------------

// x -> xs = [xh | xl] bf16 per row (row stride 1024)
__global__ void prep_x(const float* __restrict__ x, u16* __restrict__ xs)
{
    int t = blockIdx.x * 256 + threadIdx.x;       // 2*16384*512/4
    int n = t >> 7, e4 = (t & 127) << 2;
    f32x4 v = *(const f32x4*)(x + (size_t)n * 512 + e4);
    u16x4 hi, lo;
#pragma unroll
    for (int j = 0; j < 4; j++) {
        u16 h = f2bf(v[j]);
        hi[j] = h;
        lo[j] = f2bf(v[j] - bf2f(h));
    }
    *(u16x4*)(xs + (size_t)n * 1024 + e4)       = hi;
    *(u16x4*)(xs + (size_t)n * 1024 + 512 + e4) = lo;
}

// which 0/1/2: CKF/CQF fp32, wV bf16 (composed with Wx); which 3: Wo -> bf16.
__global__ void prep_w(const float* Wk, const float* Wcq, const float* Wv,
                       const float* Wx, const float* Wo,
                       float* CKF, float* CQF, u16* wV, u16* wo16)
{
    int idx = blockIdx.x * 256 + threadIdx.x;     // 4*512*512
    int which = idx >> 18;
    int rem = idx & 262143;
    if (which == 3) { wo16[rem] = f2bf(Wo[rem]); return; }
    int c = rem >> 9, e = rem & 511;
    int h = c >> 6, d = c & 63;
    const float* W = which == 0 ? Wk : (which == 1 ? Wcq : Wv);
    float s = 0.f;
#pragma unroll 8
    for (int j = 0; j < 64; j++)
        s += W[d * 64 + j] * Wx[(h * 64 + j) * 512 + e];
    if (which == 0)      CKF[(size_t)c * 512 + e] = s;
    else if (which == 1) CQF[(size_t)c * 512 + e] = s;
    else                 wV [(size_t)c * 512 + e] = f2bf(s);
}

// Composed biases: biasKQ[0..511]=k-bias(h,d), [512..1023]=q-bias; biasV.
__global__ void prep_bias(const float* Wk, const float* Wcq, const float* Wv,
                          const float* bk, const float* bcq, const float* bv,
                          const float* bx, float* biasKQ, float* biasV)
{
    int t = blockIdx.x * 256 + threadIdx.x;       // 1536
    if (t < 1024) {
        const float* W  = (t < 512) ? Wk : Wcq;
        const float* bb = (t < 512) ? bk : bcq;
        int c = t & 511; int h = c >> 6, d = c & 63;
        float s = bb[d];
        for (int j = 0; j < 64; j++) s += W[d * 64 + j] * bx[h * 64 + j];
        biasKQ[t] = s;
    } else if (t < 1536) {
        int c = t - 1024; int h = c >> 6, d = c & 63;
        float s = bv[d];
        for (int j = 0; j < 64; j++) s += Wv[d * 64 + j] * bx[h * 64 + j];
        biasV[c] = s;
    }
}

// context: kc fp32 [bh][s][d]; vcT bf16 [bh][d][s] pre-scaled by (1-sigmoid(smix)).
__global__ void prep_ctx(const float* ctx, const float* Wck, const float* bck,
                         const float* Wcv, const float* bcv, const float* smix,
                         float* kcf, u16* vcT)
{
    int t = blockIdx.x * 256 + threadIdx.x;       // 16*64*64
    int bh = t >> 12, r = t & 4095;
    int s_ = r >> 6, d = r & 63;
    const float* crow = ctx + ((size_t)bh * 64 + s_) * 64;
    float kc = bck[d], vc = bcv[d];
#pragma unroll 8
    for (int e = 0; e < 64; e++) {
        float ce = crow[e];
        kc += ce * Wck[d * 64 + e];
        vc += ce * Wcv[d * 64 + e];
    }
    kcf[(size_t)bh * 4096 + s_ * 64 + d] = kc;
    float w = 1.f / (1.f + __expf(-smix[0]));
    vcT[(size_t)bh * 4096 + d * 64 + s_] = f2bf((1.f - w) * vc);
}

// Merged: kg rows (BigB 0..511, both b), kq rows (BigB 512+hs), CC consts.
__global__ void prep_b2(const float* CKF, const float* CQF, const float* qg,
                        const float* kcf, const float* biasKQ, u16* BigB, float* CC)
{
    int idx = blockIdx.x * 256 + threadIdx.x;     // 262144 + 524288 + 1536
    if (idx < 262144) {
        int hm = idx >> 9, e = idx & 511;
        int h = hm >> 6;
        float s = 0.f;
#pragma unroll 8
        for (int d = 0; d < 64; d++)
            s += CKF[(size_t)(h * 64 + d) * 512 + e] * qg[(size_t)hm * 64 + d];
        u16 hi = f2bf(s), lo = f2bf(s - bf2f(hi));
#pragma unroll
        for (int b = 0; b < 2; b++) {
            size_t base = (size_t)b * 1572864 + (size_t)hm * 1536;
            BigB[base + e]        = lo;
            BigB[base + 512 + e]  = hi;
            BigB[base + 1024 + e] = hi;
        }
    } else if (idx < 786432) {
        int i2 = idx - 262144;
        int r = i2 >> 9, e = i2 & 511;
        int b = r >> 9, hs = r & 511;
        int h = hs >> 6, s_ = hs & 63;
        float s = 0.f;
#pragma unroll 8
        for (int d = 0; d < 64; d++)
            s += CQF[(size_t)(h * 64 + d) * 512 + e]
               * kcf[(size_t)(b * 8 + h) * 4096 + s_ * 64 + d];
        u16 hi = f2bf(s), lo = f2bf(s - bf2f(hi));
        size_t base = (size_t)b * 1572864 + (size_t)(512 + hs) * 1536;
        BigB[base + e]        = lo;
        BigB[base + 512 + e]  = hi;
        BigB[base + 1024 + e] = hi;
    } else if (idx < 787968) {
        int t = idx - 786432;                     // 0..1535
        if (t < 512) {
            int h = t >> 6;
            float s = 0.f;
            for (int d = 0; d < 64; d++) s += biasKQ[h * 64 + d] * qg[(size_t)t * 64 + d];
            CC[t] = s; CC[1024 + t] = s;
        } else {
            int j = t - 512;
            int b = j >> 9, hs = j & 511;
            int h = hs >> 6, s_ = hs & 63;
            float s = 0.f;
            for (int d = 0; d < 64; d++)
                s += biasKQ[512 + h * 64 + d]
                   * kcf[(size_t)(b * 8 + h) * 4096 + s_ * 64 + d];
            CC[b * 1024 + 512 + hs] = s;
        }
    }
}

// vT = CV @ xh^T (+row bias): vT[b][hd][n]  (xh = hi half of xs, bmask=511)
__global__ __launch_bounds__(256, 2) void k_vt(const u16* wV, const u16* xs,
                                               const float* biasV, u16* vT)
{
    __shared__ u16 As[128 * 32], Bs[128 * 32];
    f32x4 acc[4][4] = {};
    int b = blockIdx.z;
    int f = blockIdx.y * gridDim.x + blockIdx.x;       // 512 blocks per z
    int w = (f & 7) * 64 + (f >> 3);
    int trow = (w & 3) * 128;
    int tcol = (w >> 2) * 128;
    gemm_core<128, 128, 2, 2>(wV, 512, MASK_NONE, 0,
                              xs + (size_t)b * 16777216, 1024, 511u, 0,
                              512, trow, tcol, As, Bs, acc);
    int tid = threadIdx.x, wid = tid >> 6, lane = tid & 63;
    int wr = (wid & 1) * 64, wc = (wid >> 1) * 64;
    int g = lane >> 4, li = lane & 15;
#pragma unroll
    for (int fm = 0; fm < 4; fm++)
#pragma unroll
        for (int fn = 0; fn < 4; fn++) {
            int col = tcol + wc + fn * 16 + li;
#pragma unroll
            for (int j = 0; j < 4; j++) {
                int a = trow + wr + fm * 16 + g * 4 + j;
                vT[((size_t)b * 512 + a) * 16384 + col] = f2bf(acc[fm][fn][j] + biasV[a]);
            }
        }
}

// ---------------------------------------------------------------------------
// k_Ldec: dec/enc logit cols. 128n x 64(m) per block, head h = jt.
// 4 waves x (32 rows x 64 cols), acc[2][4]. E=exp(L+c1); dec-softmax over m
// (in-wave) -> P1n; den_enc partials -> denp; den_dec -> DD.
// ---------------------------------------------------------------------------
__global__ void k_Ldec(const u16* xs, const u16* BigB, const float* CC,
                       u16* P1n, float* DD, float* denp)
{
    __shared__ u16 As[128 * 32], Bs[64 * 32];
    f32x4 acc[2][4] = {};
    int f = blockIdx.x;                  // 2048
    int w = (f & 7) * 256 + (f >> 3);    // XCD-chunked, bijective
    int jt = w & 7, nb = w >> 3;
    int b = nb >> 7, ntile = nb & 127;
    int trow = ntile * 128, tcol = jt * 64;
    gemm_core<128, 64, 4, 1>(xs + (size_t)b * 16777216, 1024, 1023u, 0,
                             BigB + (size_t)b * 1572864, 1536, MASK_NONE, 0,
                             1536, trow, tcol, As, Bs, acc);
    int tid = threadIdx.x, wid = tid >> 6, lane = tid & 63;
    int wr = wid * 32;
    int g = lane >> 4, li = lane & 15;
    int h = jt;
    float cj[4];
#pragma unroll
    for (int fn = 0; fn < 4; fn++) cj[fn] = CC[b * 1024 + tcol + fn * 16 + li];

    float colsum[4] = {0.f, 0.f, 0.f, 0.f};
#pragma unroll
    for (int fm = 0; fm < 2; fm++)
#pragma unroll
        for (int j = 0; j < 4; j++) {
            float ev[4]; float dsum = 0.f;
#pragma unroll
            for (int fn = 0; fn < 4; fn++) {
                ev[fn] = __expf(acc[fm][fn][j] + cj[fn]);
                dsum += ev[fn];
                colsum[fn] += ev[fn];
            }
            dsum += __shfl_xor(dsum, 1); dsum += __shfl_xor(dsum, 2);
            dsum += __shfl_xor(dsum, 4); dsum += __shfl_xor(dsum, 8);
            float inv = 1.f / dsum;
            int row = trow + wr + fm * 16 + g * 4 + j;
            size_t pb = ((size_t)b * 16384 + row) * 512 + h * 64;
#pragma unroll
            for (int fn = 0; fn < 4; fn++)
                P1n[pb + fn * 16 + li] = f2bf(ev[fn] * inv);
            if (li == 0) DD[(size_t)(b * 8 + h) * 16384 + row] = dsum;
        }
#pragma unroll
    for (int fn = 0; fn < 4; fn++) {
        float cs = colsum[fn];
        cs += __shfl_xor(cs, 16); cs += __shfl_xor(cs, 32);
        if (lane < 16)
            denp[(size_t)(b * 512 + h * 64 + fn * 16 + li) * 512 + ntile * 4 + wid] = cs;
    }
}

// ---------------------------------------------------------------------------
// k_Lcross: cross logit cols. 128n x 64(s) per block, head h2 = jt.
// softmax over s (in-wave) -> P2L (16KB LDS, aliases As/Bs) -> PV2 vs vcT
// (B-fragments direct from global, L2-resident) -> OM2.
// ---------------------------------------------------------------------------
__global__ void k_Lcross(const u16* xs, const u16* BigB, const float* CC,
                         const u16* vcT, u16* OM2)
{
    __shared__ u16 sh[8192];             // As 0..4095 | Bs 4096..6143 ; P2L = all
    u16* As = sh; u16* Bs = sh + 4096;
    u16* P2L = sh;                       // 128 x 64 u16, XOR-swizzled
    f32x4 acc[2][4] = {};
    int f = blockIdx.x;                  // 2048
    int w = (f & 7) * 256 + (f >> 3);
    int jt = w & 7, nb = w >> 3;
    int b = nb >> 7, ntile = nb & 127;
    int trow = ntile * 128, tcol = 512 + jt * 64;
    gemm_core<128, 64, 4, 1>(xs + (size_t)b * 16777216, 1024, 1023u, 0,
                             BigB + (size_t)b * 1572864, 1536, MASK_NONE, 0,
                             1536, trow, tcol, As, Bs, acc);
    int tid = threadIdx.x, wid = tid >> 6, lane = tid & 63;
    int wr = wid * 32;
    int g = lane >> 4, li = lane & 15;
    int lrow = lane & 15, lk = g * 8;
    int h2 = jt;
    float cj[4];
#pragma unroll
    for (int fn = 0; fn < 4; fn++) cj[fn] = CC[b * 1024 + tcol + fn * 16 + li];

    __syncthreads();                     // all waves done reading As/Bs
#pragma unroll
    for (int fm = 0; fm < 2; fm++)
#pragma unroll
        for (int j = 0; j < 4; j++) {
            float ev[4]; float ssum = 0.f;
#pragma unroll
            for (int fn = 0; fn < 4; fn++) {
                ev[fn] = __expf(acc[fm][fn][j] + cj[fn]);
                ssum += ev[fn];
            }
            ssum += __shfl_xor(ssum, 1); ssum += __shfl_xor(ssum, 2);
            ssum += __shfl_xor(ssum, 4); ssum += __shfl_xor(ssum, 8);
            float inv = 1.f / ssum;
            int rl = wr + fm * 16 + g * 4 + j;
#pragma unroll
            for (int fn = 0; fn < 4; fn++) {
                int s = fn * 16 + li;
                P2L[rl * 64 + (s ^ ((rl & 7) << 3))] = f2bf(ev[fn] * inv);
            }
        }
    __syncthreads();
    // PV2: out2[n][d] = sum_s P2[n][s] * vcT[d][s]
    const u16* vcg = vcT + (size_t)(b * 8 + h2) * 4096;
    f32x4 oacc[2][4] = {};
#pragma unroll
    for (int kt = 0; kt < 64; kt += 32) {
        bf16x8 paf[2], vbf[4];
#pragma unroll
        for (int fm = 0; fm < 2; fm++) {
            int r = wr + fm * 16 + lrow;
            paf[fm] = *(const bf16x8*)&P2L[r * 64 + ((kt + lk) ^ ((r & 7) << 3))];
        }
#pragma unroll
        for (int fn = 0; fn < 4; fn++) {
            int d2 = fn * 16 + lrow;
            vbf[fn] = *(const bf16x8*)&vcg[d2 * 64 + kt + lk];
        }
#pragma unroll
        for (int fm = 0; fm < 2; fm++)
#pragma unroll
            for (int fn = 0; fn < 4; fn++)
                oacc[fm][fn] = __builtin_amdgcn_mfma_f32_16x16x32_bf16(
                    paf[fm], vbf[fn], oacc[fm][fn], 0, 0, 0);
    }
#pragma unroll
    for (int fm = 0; fm < 2; fm++)
#pragma unroll
        for (int fn = 0; fn < 4; fn++)
#pragma unroll
            for (int j = 0; j < 4; j++) {
                int rl = wr + fm * 16 + g * 4 + j;
                OM2[((size_t)b * 16384 + trow + rl) * 512 + h2 * 64 + fn * 16 + li]
                    = f2bf(oacc[fm][fn][j]);
            }
}

// ---------------------------------------------------------------------------
// latT: latp[ch][bh][d][m] = sum_n vT[d][n] * (P1n[n][h,m]*DD[n])  (split-K 16)
// ---------------------------------------------------------------------------
__global__ __launch_bounds__(256, 2) void k_latT(const u16* vT, const u16* P1n,
                                                 const float* DD, float* latp)
{
    __shared__ u16 As[64 * 32], Bs[64 * 32];
    f32x4 acc[2][2] = {};
    int ch = blockIdx.x, bh = blockIdx.z;
    int b = bh >> 3, h = bh & 7;
    int koff = ch * 1024;
    int tid = threadIdx.x, wid = tid >> 6, lane = tid & 63;
    int wr = (wid & 1) * 32, wc = (wid >> 1) * 32;
    int lrow = lane & 15, lk = (lane >> 4) * 8;
    const u16* Avt = vT + (size_t)bh * 64 * 16384;

    for (int kt = 0; kt < 1024; kt += 32) {
        __syncthreads();
        {   // stage A: vT rows 64 x 32k
            int row = tid >> 2, kg = tid & 3;
            gload16(Avt + (size_t)row * 16384 + koff + kt + kg * 8, As + (size_t)tid * 8);
        }
        {   // stage B transposed: Bs[m][n], XOR-swizzled (n ^ ((m&3)<<3))
            int nl = tid & 31, m0 = (tid >> 5) * 8;
            int n = koff + kt + nl;
            const u16* src = P1n + ((size_t)b * 16384 + n) * 512 + h * 64 + m0;
            u16x4 p0 = *(const u16x4*)src;
            u16x4 p1 = *(const u16x4*)(src + 4);
            float ddv = DD[(size_t)bh * 16384 + n];
#pragma unroll
            for (int i = 0; i < 4; i++) {
                int m = m0 + i;
                Bs[m * 32 + (nl ^ ((m & 3) << 3))] = f2bf(bf2f(p0[i]) * ddv);
            }
#pragma unroll
            for (int i = 0; i < 4; i++) {
                int m = m0 + 4 + i;
                Bs[m * 32 + (nl ^ ((m & 3) << 3))] = f2bf(bf2f(p1[i]) * ddv);
            }
        }
        __syncthreads();
        bf16x8 af[2], bfv[2];
#pragma unroll
        for (int fm = 0; fm < 2; fm++)
            af[fm] = *(const bf16x8*)&As[(wr + fm * 16 + lrow) * 32 + lk];
#pragma unroll
        for (int fn = 0; fn < 2; fn++) {
            int m = wc + fn * 16 + lrow;
            bfv[fn] = *(const bf16x8*)&Bs[m * 32 + (lk ^ ((m & 3) << 3))];
        }
#pragma unroll
        for (int fm = 0; fm < 2; fm++)
#pragma unroll
            for (int fn = 0; fn < 2; fn++)
                acc[fm][fn] = __builtin_amdgcn_mfma_f32_16x16x32_bf16(
                    af[fm], bfv[fn], acc[fm][fn], 0, 0, 0);
    }
    float* C = latp + ((size_t)ch * 16 + bh) * 4096;
    int g = lane >> 4, li = lane & 15;
#pragma unroll
    for (int fm = 0; fm < 2; fm++)
#pragma unroll
        for (int fn = 0; fn < 2; fn++)
#pragma unroll
            for (int j = 0; j < 4; j++) {
                int row = wr + fm * 16 + g * 4 + j;   // d
                int col = wc + fn * 16 + li;          // m
                C[row * 64 + col] = acc[fm][fn][j];
            }
}

__global__ void k_rden(const float* denp, float* dene)
{
    int t = blockIdx.x * 256 + threadIdx.x;       // 1024
    if (t < 1024) {
        float s = 0.f;
        const float* p = denp + (size_t)t * 512;
        for (int i = 0; i < 512; i++) s += p[i];
        dene[t] = s;
    }
}

// finish latent: latB[bh][d][m] = w * (sum_ch latp)/den_enc[m]
__global__ void k_latfin(const float* latp, const float* dene, const float* smix,
                         u16* latB)
{
    int t = blockIdx.x * 256 + threadIdx.x;       // 16*64*64
    int bh = t >> 12, r = t & 4095;
    int m = r & 63;
    float w = 1.f / (1.f + __expf(-smix[0]));
    float s = 0.f;
    for (int c = 0; c < 16; c++) s += latp[((size_t)c * 16 + bh) * 4096 + r];
    int b = bh >> 3, h = bh & 7;
    float lat = s / dene[b * 512 + h * 64 + m];
    latB[(size_t)bh * 4096 + r] = f2bf(w * lat);
}

// ---------------------------------------------------------------------------
// k_om: OM[n][h*64+d] = sum_m P1n[n][h,m] * latB[bh][d][m] + OM2[n][h*64+d]
// ---------------------------------------------------------------------------
__global__ __launch_bounds__(256, 2) void k_om(const u16* P1n, const u16* latB,
                                               const u16* OM2, u16* OM)
{
    __shared__ u16 As[128 * 64], Bs2[64 * 64];
    int b = blockIdx.z, ntile = blockIdx.x;
    int tid = threadIdx.x, wid = tid >> 6, lane = tid & 63;
    int g = lane >> 4, li = lane & 15;
    int lrow = lane & 15, lk = g * 8;
    for (int h = 0; h < 8; h++) {
        __syncthreads();
#pragma unroll
        for (int i = 0; i < 4; i++) {     // stage A 128n x 64m swizzled
            int c = i * 256 + tid;
            int n = c >> 3, m0 = (c & 7) * 8;
            gload16(P1n + ((size_t)b * 16384 + ntile * 128 + n) * 512 + h * 64
                         + (m0 ^ ((n & 7) << 3)), As + (size_t)c * 8);
        }
#pragma unroll
        for (int i = 0; i < 2; i++) {     // stage B 64d x 64m swizzled
            int c = i * 256 + tid;
            int d = c >> 3, m0 = (c & 7) * 8;
            gload16(latB + (size_t)(b * 8 + h) * 4096 + d * 64
                         + (m0 ^ ((d & 7) << 3)), Bs2 + (size_t)c * 8);
        }
        __syncthreads();
        f32x4 oacc[2][4] = {};
#pragma unroll
        for (int kt = 0; kt < 64; kt += 32) {
            bf16x8 af[2], bfv[4];
#pragma unroll
            for (int fm = 0; fm < 2; fm++) {
                int r = wid * 32 + fm * 16 + lrow;
                af[fm] = *(const bf16x8*)&As[r * 64 + ((kt + lk) ^ ((r & 7) << 3))];
            }
#pragma unroll
            for (int fn = 0; fn < 4; fn++) {
                int d = fn * 16 + lrow;
                bfv[fn] = *(const bf16x8*)&Bs2[d * 64 + ((kt + lk) ^ ((d & 7) << 3))];
            }
#pragma unroll
            for (int fm = 0; fm < 2; fm++)
#pragma unroll
                for (int fn = 0; fn < 4; fn++)
                    oacc[fm][fn] = __builtin_amdgcn_mfma_f32_16x16x32_bf16(
                        af[fm], bfv[fn], oacc[fm][fn], 0, 0, 0);
        }
#pragma unroll
        for (int fm = 0; fm < 2; fm++)
#pragma unroll
            for (int fn = 0; fn < 4; fn++)
#pragma unroll
                for (int j = 0; j < 4; j++) {
                    int rl = wid * 32 + fm * 16 + g * 4 + j;
                    size_t addr = ((size_t)b * 16384 + ntile * 128 + rl) * 512
                                  + h * 64 + fn * 16 + li;
                    OM[addr] = f2bf(oacc[fm][fn][j] + bf2f(OM2[addr]));
                }
    }
}

// final: out(fp32) = OM @ Wo^T + bo.
__global__ __launch_bounds__(256, 2) void k_f(const u16* OM, const u16* wo16,
                                              const float* bo, float* out)
{
    __shared__ u16 As[128 * 32], Bs[128 * 32];
    f32x4 acc[4][4] = {};
    int f = blockIdx.y * gridDim.x + blockIdx.x;       // 1024 blocks
    int w = (f & 7) * 128 + (f >> 3);
    int tcol = (w & 3) * 128, trow = (w >> 2) * 128;
    gemm_core<128, 128, 2, 2>(OM, 512, MASK_NONE, 0, wo16, 512, MASK_NONE, 0,
                              512, trow, tcol, As, Bs, acc);
    int tid = threadIdx.x, wid = tid >> 6, lane = tid & 63;
    int wr = (wid & 1) * 64, wc = (wid >> 1) * 64;
    int g = lane >> 4, li = lane & 15;
#pragma unroll
    for (int fm = 0; fm < 4; fm++)
#pragma unroll
        for (int fn = 0; fn < 4; fn++) {
            int col = tcol + wc + fn * 16 + li;
            float bias = bo[col];
#pragma unroll
            for (int j = 0; j < 4; j++) {
                int row = trow + wr + fm * 16 + g * 4 + j;
                out[(size_t)row * 512 + col] = acc[fm][fn][j] + bias;
            }
        }
}

// ---------------------------------------------------------------------------
// Workspace layout (bytes), end ~185 MB (< proven-safe 209.7 MB).
// OM aliases XS (xs dead after k_Ldec/k_Lcross; k_om runs after).
// ---------------------------------------------------------------------------
static const size_t XS_OFF   = 0;            // u16 32768x1024   (67,108,864)
static const size_t OMB_OFF  = 0;            // u16 32768x512    (alias XS)
static const size_t P1N_OFF  = 67108864;     // u16 2x16384x512  (33,554,432)
static const size_t OM2_OFF  = 100663296;    // u16 2x16384x512  (33,554,432)
static const size_t VT_OFF   = 134217728;    // u16 2x512x16384  (33,554,432)
static const size_t CKF_OFF  = 167772160;    // f32 512x512      (1,048,576)
static const size_t CQF_OFF  = 168820736;    // f32 512x512      (1,048,576)
static const size_t WV_OFF   = 169869312;    // u16 512x512      (524,288)
static const size_t WO_OFF   = 170393600;    // u16 512x512      (524,288)
static const size_t BIGB_OFF = 170917888;    // u16 2x1024x1536  (6,291,456)
static const size_t KCF_OFF  = 177209344;    // f32 16x64x64     (262,144)
static const size_t VCT_OFF  = 177471488;    // u16 16x64x64     (131,072)
static const size_t BKQ_OFF  = 177602560;    // f32 1024         (4,096)
static const size_t BV_OFF   = 177606656;    // f32 512          (2,048)
static const size_t CC_OFF   = 177608704;    // f32 2048         (8,192)
static const size_t DENP_OFF = 177616896;    // f32 1024x512     (2,097,152)
static const size_t DENE_OFF = 179714048;    // f32 1024         (4,096)
static const size_t DD_OFF   = 179718144;    // f32 16x16384     (1,048,576)
static const size_t LATP_OFF = 180766720;    // f32 16x16x64x64  (4,194,304)
static const size_t LATB_OFF = 184961024;    // u16 16x64x64     (131,072)
// end: 185,092,096

extern "C" void kernel_launch(void* const* d_in, const int* in_sizes, int n_in,
                              void* d_out, int out_size, void* d_ws, size_t ws_size,
                              hipStream_t stream)
{
    const float* x    = (const float*)d_in[0];
    const float* ctx  = (const float*)d_in[1];
    const float* qg   = (const float*)d_in[2];
    const float* Wx   = (const float*)d_in[3];
    const float* bx   = (const float*)d_in[4];
    const float* Wk   = (const float*)d_in[5];
    const float* bk   = (const float*)d_in[6];
    const float* Wv   = (const float*)d_in[7];
    const float* bv   = (const float*)d_in[8];
    const float* Wcq  = (const float*)d_in[9];
    const float* bcq  = (const float*)d_in[10];
    const float* Wck  = (const float*)d_in[11];
    const float* bck  = (const float*)d_in[12];
    const float* Wcv  = (const float*)d_in[13];
    const float* bcv  = (const float*)d_in[14];
    const float* smix = (const float*)d_in[15];
    const float* Wo   = (const float*)d_in[16];
    const float* bo   = (const float*)d_in[17];

    char* ws = (char*)d_ws;
    u16*   xs    = (u16*)  (ws + XS_OFF);
    u16*   OM    = (u16*)  (ws + OMB_OFF);
    u16*   P1n   = (u16*)  (ws + P1N_OFF);
    u16*   OM2   = (u16*)  (ws + OM2_OFF);
    u16*   vT    = (u16*)  (ws + VT_OFF);
    float* CKF   = (float*)(ws + CKF_OFF);
    float* CQF   = (float*)(ws + CQF_OFF);
    u16*   wV    = (u16*)  (ws + WV_OFF);
    u16*   wo16  = (u16*)  (ws + WO_OFF);
    u16*   BigB  = (u16*)  (ws + BIGB_OFF);
    float* kcf   = (float*)(ws + KCF_OFF);
    u16*   vcT   = (u16*)  (ws + VCT_OFF);
    float* biasKQ= (float*)(ws + BKQ_OFF);
    float* biasV = (float*)(ws + BV_OFF);
    float* CC    = (float*)(ws + CC_OFF);
    float* denp  = (float*)(ws + DENP_OFF);
    float* dene  = (float*)(ws + DENE_OFF);
    float* DD    = (float*)(ws + DD_OFF);
    float* latp  = (float*)(ws + LATP_OFF);
    u16*   latB  = (u16*)  (ws + LATB_OFF);

    prep_w   <<< 4096, 256, 0, stream>>>(Wk, Wcq, Wv, Wx, Wo, CKF, CQF, wV, wo16);
    prep_bias<<<    6, 256, 0, stream>>>(Wk, Wcq, Wv, bk, bcq, bv, bx, biasKQ, biasV);
    prep_ctx <<<  256, 256, 0, stream>>>(ctx, Wck, bck, Wcv, bcv, smix, kcf, vcT);
    prep_x   <<<16384, 256, 0, stream>>>(x, xs);
    prep_b2  <<< 3078, 256, 0, stream>>>(CKF, CQF, qg, kcf, biasKQ, BigB, CC);

    k_vt    <<<dim3(128,   4, 2), 256, 0, stream>>>(wV, xs, biasV, vT);
    k_Ldec  <<<2048, 256, 0, stream>>>(xs, BigB, CC, P1n, DD, denp);
    k_Lcross<<<2048, 256, 0, stream>>>(xs, BigB, CC, vcT, OM2);
    k_latT  <<<dim3( 16,   1, 16), 256, 0, stream>>>(vT, P1n, DD, latp);
    k_rden  <<<    4, 256, 0, stream>>>(denp, dene);
    k_latfin<<<  256, 256, 0, stream>>>(latp, dene, smix, latB);
    k_om    <<<dim3(128,   1, 2), 256, 0, stream>>>(P1n, latB, OM2, OM);
    k_f     <<<dim3(  4, 256, 1), 256, 0, stream>>>(OM, wo16, bo, (float*)d_out);
}

// Round 9
// 392.689 us; speedup vs baseline: 1.0708x; 1.0191x over previous
//
#include <hip/hip_runtime.h>

// ---------------------------------------------------------------------------
// GALE_FA: FLARE low-rank self-attn + context cross-attn + gated mix.
// R4: logits computed directly from x (k/q never materialized).
// R8: K-cut 1536->1024 (drop xl*Bhi term; kg/kq still fp32-split vs bf16 x),
// xs = hi-only (32MB), R5 128x128 tiles restored, den_enc moved to k_dene.
// ---------------------------------------------------------------------------

typedef unsigned short u16;
typedef __attribute__((ext_vector_type(4))) float  f32x4;
typedef __attribute__((ext_vector_type(4))) u16    u16x4;
typedef __attribute__((ext_vector_type(8))) __bf16 bf16x8;

__device__ __forceinline__ float bf2f(u16 u) {
    return __uint_as_float(((unsigned)u) << 16);
}
__device__ __forceinline__ u16 f2bf(float f) {   // round-to-nearest-even
    unsigned u = __float_as_uint(f);
    u += 0x7fffu + ((u >> 16) & 1u);
    return (u16)(u >> 16);
}
__device__ __forceinline__ void gload16(const void* g, void* l) {
    __builtin_amdgcn_global_load_lds(
        (const __attribute__((address_space(1))) unsigned int*)g,
        (__attribute__((address_space(3))) unsigned int*)l, 16, 0, 0);
}

#define MASK_NONE 0x7fffffffu

// ---------------------------------------------------------------------------
// Generic MFMA GEMM core (m97-style 2-barrier loop, BK=32), 256 threads.
// ---------------------------------------------------------------------------
template<int BM, int BN, int WMW, int WNW>
__device__ __forceinline__ void gemm_core(
    const u16* __restrict__ A, int lda, unsigned amask, int koffA,
    const u16* __restrict__ Bm, int ldb, unsigned bmask, int koffB,
    int K, int trow, int tcol,
    u16* As, u16* Bs,
    f32x4 (&acc)[BM / WMW / 16][BN / WNW / 16])
{
    constexpr int FM = BM / WMW / 16;
    constexpr int FN = BN / WNW / 16;
    const int tid  = threadIdx.x;
    const int wid  = tid >> 6, lane = tid & 63;
    const int wm   = wid % WMW, wn = wid / WMW;
    const int wr   = wm * (BM / WMW), wc = wn * (BN / WNW);
    const int lrow = lane & 15, lk = (lane >> 4) * 8;

    for (int kt = 0; kt < K; kt += 32) {
        __syncthreads();
#pragma unroll
        for (int i = 0; i < BM / 64; i++) {           // stage A tile
            int c = i * 256 + tid;
            int row = c >> 2, kg = c & 3;
            unsigned kk = ((unsigned)(koffA + kt + kg * 8)) & amask;
            gload16(A + (size_t)(trow + row) * lda + kk, As + (size_t)c * 8);
        }
#pragma unroll
        for (int i = 0; i < BN / 64; i++) {           // stage B tile
            int c = i * 256 + tid;
            int col = c >> 2, kg = c & 3;
            unsigned kk = ((unsigned)(koffB + kt + kg * 8)) & bmask;
            gload16(Bm + (size_t)(tcol + col) * ldb + kk, Bs + (size_t)c * 8);
        }
        __syncthreads();

        bf16x8 af[FM], bfr[FN];
#pragma unroll
        for (int fm = 0; fm < FM; fm++)
            af[fm] = *(const bf16x8*)&As[(wr + fm * 16 + lrow) * 32 + lk];
#pragma unroll
        for (int fn = 0; fn < FN; fn++)
            bfr[fn] = *(const bf16x8*)&Bs[(wc + fn * 16 + lrow) * 32 + lk];
#pragma unroll
        for (int fm = 0; fm < FM; fm++)
#pragma unroll
            for (int fn = 0; fn < FN; fn++)
                acc[fm][fn] = __builtin_amdgcn_mfma_f32_16x16x32_bf16(
                    af[fm], bfr[fn], acc[fm][fn], 0, 0, 0);
    }
}

// ---------------------------------------------------------------------------
// Prep kernels (fp32 inputs)
// ---------------------------------------------------------------------------

// x -> xs = bf16(x) (hi only, row stride 512)
__global__ void prep_x(const float* __restrict__ x, u16* __restrict__ xs)
{
    int t = blockIdx.x * 256 + threadIdx.x;       // 2*16384*512/4
    int n = t >> 7, e4 = (t & 127) << 2;
    f32x4 v = *(const f32x4*)(x + (size_t)n * 512 + e4);
    u16x4 hi;
#pragma unroll
    for (int j = 0; j < 4; j++) hi[j] = f2bf(v[j]);
    *(u16x4*)(xs + (size_t)n * 512 + e4) = hi;
}

// which 0/1/2: CKF/CQF fp32, wV bf16 (composed with Wx); which 3: Wo -> bf16.
__global__ void prep_w(const float* Wk, const float* Wcq, const float* Wv,
                       const float* Wx, const float* Wo,
                       float* CKF, float* CQF, u16* wV, u16* wo16)
{
    int idx = blockIdx.x * 256 + threadIdx.x;     // 4*512*512
    int which = idx >> 18;
    int rem = idx & 262143;
    if (which == 3) { wo16[rem] = f2bf(Wo[rem]); return; }
    int c = rem >> 9, e = rem & 511;
    int h = c >> 6, d = c & 63;
    const float* W = which == 0 ? Wk : (which == 1 ? Wcq : Wv);
    float s = 0.f;
#pragma unroll 8
    for (int j = 0; j < 64; j++)
        s += W[d * 64 + j] * Wx[(h * 64 + j) * 512 + e];
    if (which == 0)      CKF[(size_t)c * 512 + e] = s;
    else if (which == 1) CQF[(size_t)c * 512 + e] = s;
    else                 wV [(size_t)c * 512 + e] = f2bf(s);
}

// Composed biases: biasKQ[0..511]=k-bias(h,d), [512..1023]=q-bias; biasV.
__global__ void prep_bias(const float* Wk, const float* Wcq, const float* Wv,
                          const float* bk, const float* bcq, const float* bv,
                          const float* bx, float* biasKQ, float* biasV)
{
    int t = blockIdx.x * 256 + threadIdx.x;       // 1536
    if (t < 1024) {
        const float* W  = (t < 512) ? Wk : Wcq;
        const float* bb = (t < 512) ? bk : bcq;
        int c = t & 511; int h = c >> 6, d = c & 63;
        float s = bb[d];
        for (int j = 0; j < 64; j++) s += W[d * 64 + j] * bx[h * 64 + j];
        biasKQ[t] = s;
    } else if (t < 1536) {
        int c = t - 1024; int h = c >> 6, d = c & 63;
        float s = bv[d];
        for (int j = 0; j < 64; j++) s += Wv[d * 64 + j] * bx[h * 64 + j];
        biasV[c] = s;
    }
}

// context: kc fp32 [bh][s][d]; vcT bf16 [bh][d][s] pre-scaled by (1-sigmoid(smix)).
__global__ void prep_ctx(const float* ctx, const float* Wck, const float* bck,
                         const float* Wcv, const float* bcv, const float* smix,
                         float* kcf, u16* vcT)
{
    int t = blockIdx.x * 256 + threadIdx.x;       // 16*64*64
    int bh = t >> 12, r = t & 4095;
    int s_ = r >> 6, d = r & 63;
    const float* crow = ctx + ((size_t)bh * 64 + s_) * 64;
    float kc = bck[d], vc = bcv[d];
#pragma unroll 8
    for (int e = 0; e < 64; e++) {
        float ce = crow[e];
        kc += ce * Wck[d * 64 + e];
        vc += ce * Wcv[d * 64 + e];
    }
    kcf[(size_t)bh * 4096 + s_ * 64 + d] = kc;
    float w = 1.f / (1.f + __expf(-smix[0]));
    vcT[(size_t)bh * 4096 + d * 64 + s_] = f2bf((1.f - w) * vc);
}

// Merged: kg rows (BigB 0..511 [lo|hi], both b), kq rows (512+hs), CC consts.
__global__ void prep_b2(const float* CKF, const float* CQF, const float* qg,
                        const float* kcf, const float* biasKQ, u16* BigB, float* CC)
{
    int idx = blockIdx.x * 256 + threadIdx.x;     // 262144 + 524288 + 1536
    if (idx < 262144) {
        int hm = idx >> 9, e = idx & 511;
        int h = hm >> 6;
        float s = 0.f;
#pragma unroll 8
        for (int d = 0; d < 64; d++)
            s += CKF[(size_t)(h * 64 + d) * 512 + e] * qg[(size_t)hm * 64 + d];
        u16 hi = f2bf(s), lo = f2bf(s - bf2f(hi));
#pragma unroll
        for (int b = 0; b < 2; b++) {
            size_t base = (size_t)b * 1048576 + (size_t)hm * 1024;
            BigB[base + e]       = lo;
            BigB[base + 512 + e] = hi;
        }
    } else if (idx < 786432) {
        int i2 = idx - 262144;
        int r = i2 >> 9, e = i2 & 511;
        int b = r >> 9, hs = r & 511;
        int h = hs >> 6, s_ = hs & 63;
        float s = 0.f;
#pragma unroll 8
        for (int d = 0; d < 64; d++)
            s += CQF[(size_t)(h * 64 + d) * 512 + e]
               * kcf[(size_t)(b * 8 + h) * 4096 + s_ * 64 + d];
        u16 hi = f2bf(s), lo = f2bf(s - bf2f(hi));
        size_t base = (size_t)b * 1048576 + (size_t)(512 + hs) * 1024;
        BigB[base + e]       = lo;
        BigB[base + 512 + e] = hi;
    } else if (idx < 787968) {
        int t = idx - 786432;                     // 0..1535
        if (t < 512) {
            int h = t >> 6;
            float s = 0.f;
            for (int d = 0; d < 64; d++) s += biasKQ[h * 64 + d] * qg[(size_t)t * 64 + d];
            CC[t] = s; CC[1024 + t] = s;
        } else {
            int j = t - 512;
            int b = j >> 9, hs = j & 511;
            int h = hs >> 6, s_ = hs & 63;
            float s = 0.f;
            for (int d = 0; d < 64; d++)
                s += biasKQ[512 + h * 64 + d]
                   * kcf[(size_t)(b * 8 + h) * 4096 + s_ * 64 + d];
            CC[b * 1024 + 512 + hs] = s;
        }
    }
}

// vT = CV @ xs^T (+row bias): vT[b][hd][n]
__global__ __launch_bounds__(256, 2) void k_vt(const u16* wV, const u16* xs,
                                               const float* biasV, u16* vT)
{
    __shared__ u16 As[128 * 32], Bs[128 * 32];
    f32x4 acc[4][4] = {};
    int b = blockIdx.z;
    int f = blockIdx.y * gridDim.x + blockIdx.x;       // 512 blocks per z
    int w = (f & 7) * 64 + (f >> 3);
    int trow = (w & 3) * 128;
    int tcol = (w >> 2) * 128;
    gemm_core<128, 128, 2, 2>(wV, 512, MASK_NONE, 0,
                              xs + (size_t)b * 8388608, 512, MASK_NONE, 0,
                              512, trow, tcol, As, Bs, acc);
    int tid = threadIdx.x, wid = tid >> 6, lane = tid & 63;
    int wr = (wid & 1) * 64, wc = (wid >> 1) * 64;
    int g = lane >> 4, li = lane & 15;
#pragma unroll
    for (int fm = 0; fm < 4; fm++)
#pragma unroll
        for (int fn = 0; fn < 4; fn++) {
            int col = tcol + wc + fn * 16 + li;
#pragma unroll
            for (int j = 0; j < 4; j++) {
                int a = trow + wr + fm * 16 + g * 4 + j;
                vT[((size_t)b * 512 + a) * 16384 + col] = f2bf(acc[fm][fn][j] + biasV[a]);
            }
        }
}

// ---------------------------------------------------------------------------
// k_Ldec: dec/enc logit cols (0..511). 128n x 128(h,m) per block, K=1024.
// E=exp(L+c1); dec-softmax over m (in-wave) -> P1n; den_dec -> DD.
// ---------------------------------------------------------------------------
__global__ void k_Ldec(const u16* xs, const u16* BigB, const float* CC,
                       u16* P1n, float* DD)
{
    __shared__ u16 As[128 * 32], Bs[128 * 32];
    f32x4 acc[4][4] = {};
    int f = blockIdx.x;                  // 1024
    int w = (f & 7) * 128 + (f >> 3);    // XCD-chunked, bijective
    int jt = w & 3, nb = w >> 2;
    int b = nb >> 7, ntile = nb & 127;
    int trow = ntile * 128, tcol = jt * 128;
    gemm_core<128, 128, 2, 2>(xs + (size_t)b * 8388608, 512, 511u, 0,
                              BigB + (size_t)b * 1048576, 1024, MASK_NONE, 0,
                              1024, trow, tcol, As, Bs, acc);
    int tid = threadIdx.x, wid = tid >> 6, lane = tid & 63;
    int wm = wid & 1, wn = wid >> 1;
    int wr = wm * 64, wc = wn * 64;
    int g = lane >> 4, li = lane & 15;
    float cj[4];
#pragma unroll
    for (int fn = 0; fn < 4; fn++) cj[fn] = CC[b * 1024 + tcol + wc + fn * 16 + li];

    int h = jt * 2 + wn;
#pragma unroll
    for (int fm = 0; fm < 4; fm++)
#pragma unroll
        for (int j = 0; j < 4; j++) {
            float ev[4]; float dsum = 0.f;
#pragma unroll
            for (int fn = 0; fn < 4; fn++) {
                ev[fn] = __expf(acc[fm][fn][j] + cj[fn]);
                dsum += ev[fn];
            }
            dsum += __shfl_xor(dsum, 1); dsum += __shfl_xor(dsum, 2);
            dsum += __shfl_xor(dsum, 4); dsum += __shfl_xor(dsum, 8);
            float inv = 1.f / dsum;
            int row = trow + wr + fm * 16 + g * 4 + j;
            size_t pb = ((size_t)b * 16384 + row) * 512 + h * 64;
#pragma unroll
            for (int fn = 0; fn < 4; fn++)
                P1n[pb + fn * 16 + li] = f2bf(ev[fn] * inv);
            if (li == 0) DD[(size_t)(b * 8 + h) * 16384 + row] = dsum;
        }
}

// ---------------------------------------------------------------------------
// k_Lcross: cross logit cols (512..1023), K=1024. softmax over s -> P2L (LDS,
// aliases As/Bs) -> PV2 vs vcT (B direct from global, L2-resident) -> OM2.
// ---------------------------------------------------------------------------
__global__ void k_Lcross(const u16* xs, const u16* BigB, const float* CC,
                         const u16* vcT, u16* OM2)
{
    __shared__ u16 sh[8192];             // As | Bs ; P2L aliases all 16KB
    u16* As = sh; u16* Bs = sh + 4096;
    u16* P2L = sh;                       // 128 x 64 u16, XOR-swizzled
    f32x4 acc[4][4] = {};
    int f = blockIdx.x;                  // 1024
    int w = (f & 7) * 128 + (f >> 3);
    int jt = w & 3, nb = w >> 2;
    int b = nb >> 7, ntile = nb & 127;
    int trow = ntile * 128, tcol = 512 + jt * 128;
    gemm_core<128, 128, 2, 2>(xs + (size_t)b * 8388608, 512, 511u, 0,
                              BigB + (size_t)b * 1048576, 1024, MASK_NONE, 0,
                              1024, trow, tcol, As, Bs, acc);
    int tid = threadIdx.x, wid = tid >> 6, lane = tid & 63;
    int wm = wid & 1, wn = wid >> 1;
    int wr = wm * 64, wc = wn * 64;
    int g = lane >> 4, li = lane & 15;
    int lrow = lane & 15, lk = g * 8;
    float cj[4];
#pragma unroll
    for (int fn = 0; fn < 4; fn++) cj[fn] = CC[b * 1024 + tcol + wc + fn * 16 + li];

    int hpair = jt * 2;
    for (int hh = 0; hh < 2; hh++) {
        __syncthreads();                 // LDS (As/Bs or prev P2L) safe to reuse
        int h2 = hpair + hh;
        const u16* vcg = vcT + (size_t)(b * 8 + h2) * 4096;
        if (wn == hh) {                  // this wave-pair's cols = head h2
#pragma unroll
            for (int fm = 0; fm < 4; fm++)
#pragma unroll
                for (int j = 0; j < 4; j++) {
                    float ev[4]; float ssum = 0.f;
#pragma unroll
                    for (int fn = 0; fn < 4; fn++) {
                        ev[fn] = __expf(acc[fm][fn][j] + cj[fn]);
                        ssum += ev[fn];
                    }
                    ssum += __shfl_xor(ssum, 1); ssum += __shfl_xor(ssum, 2);
                    ssum += __shfl_xor(ssum, 4); ssum += __shfl_xor(ssum, 8);
                    float inv = 1.f / ssum;
                    int rl = wr + fm * 16 + g * 4 + j;
#pragma unroll
                    for (int fn = 0; fn < 4; fn++) {
                        int s = fn * 16 + li;
                        P2L[rl * 64 + (s ^ ((rl & 7) << 3))] = f2bf(ev[fn] * inv);
                    }
                }
        }
        __syncthreads();
        // PV2: out2[n][d] = sum_s P2[n][s] * vcT[d][s]
        f32x4 oacc[2][4] = {};
#pragma unroll
        for (int kt = 0; kt < 64; kt += 32) {
            bf16x8 paf[2], vbf[4];
#pragma unroll
            for (int fm = 0; fm < 2; fm++) {
                int r = wid * 32 + fm * 16 + lrow;
                paf[fm] = *(const bf16x8*)&P2L[r * 64 + ((kt + lk) ^ ((r & 7) << 3))];
            }
#pragma unroll
            for (int fn = 0; fn < 4; fn++) {
                int d2 = fn * 16 + lrow;
                vbf[fn] = *(const bf16x8*)&vcg[d2 * 64 + kt + lk];
            }
#pragma unroll
            for (int fm = 0; fm < 2; fm++)
#pragma unroll
                for (int fn = 0; fn < 4; fn++)
                    oacc[fm][fn] = __builtin_amdgcn_mfma_f32_16x16x32_bf16(
                        paf[fm], vbf[fn], oacc[fm][fn], 0, 0, 0);
        }
#pragma unroll
        for (int fm = 0; fm < 2; fm++)
#pragma unroll
            for (int fn = 0; fn < 4; fn++)
#pragma unroll
                for (int j = 0; j < 4; j++) {
                    int rl = wid * 32 + fm * 16 + g * 4 + j;
                    OM2[((size_t)b * 16384 + trow + rl) * 512 + h2 * 64 + fn * 16 + li]
                        = f2bf(oacc[fm][fn][j]);
                }
    }
}

// ---------------------------------------------------------------------------
// k_dene: den_enc partials from P1n*DD: denp[(b,h,m)][c] = sum_{n in chunk c} E
// ---------------------------------------------------------------------------
__global__ void k_dene(const u16* P1n, const float* DD, float* denp)
{
    __shared__ float denL[4][64];
    int blk = blockIdx.x;                 // 256 = bh*16 + c
    int bh = blk >> 4, c = blk & 15;
    int b = bh >> 3, h = bh & 7;
    int t = threadIdx.x;
    int m = t & 63, r = (t >> 6) & 3;
    float s = 0.f;
    const u16* base = P1n + (size_t)b * 16384 * 512 + h * 64 + m;
    const float* ddb = DD + (size_t)bh * 16384;
    for (int i = 0; i < 256; i++) {
        int n = c * 1024 + i * 4 + r;
        s += bf2f(base[(size_t)n * 512]) * ddb[n];
    }
    denL[r][m] = s;
    __syncthreads();
    if (t < 64)
        denp[(size_t)(b * 512 + h * 64 + t) * 16 + c]
            = denL[0][t] + denL[1][t] + denL[2][t] + denL[3][t];
}

__global__ void k_rden(const float* denp, float* dene)
{
    int t = blockIdx.x * 256 + threadIdx.x;       // 1024
    if (t < 1024) {
        float s = 0.f;
        const float* p = denp + (size_t)t * 16;
        for (int i = 0; i < 16; i++) s += p[i];
        dene[t] = s;
    }
}

// ---------------------------------------------------------------------------
// latT: latp[ch][bh][d][m] = sum_n vT[d][n] * (P1n[n][h,m]*DD[n])  (split-K 16)
// ---------------------------------------------------------------------------
__global__ __launch_bounds__(256, 2) void k_latT(const u16* vT, const u16* P1n,
                                                 const float* DD, float* latp)
{
    __shared__ u16 As[64 * 32], Bs[64 * 32];
    f32x4 acc[2][2] = {};
    int ch = blockIdx.x, bh = blockIdx.z;
    int b = bh >> 3, h = bh & 7;
    int koff = ch * 1024;
    int tid = threadIdx.x, wid = tid >> 6, lane = tid & 63;
    int wr = (wid & 1) * 32, wc = (wid >> 1) * 32;
    int lrow = lane & 15, lk = (lane >> 4) * 8;
    const u16* Avt = vT + (size_t)bh * 64 * 16384;

    for (int kt = 0; kt < 1024; kt += 32) {
        __syncthreads();
        {   // stage A: vT rows 64 x 32k
            int row = tid >> 2, kg = tid & 3;
            gload16(Avt + (size_t)row * 16384 + koff + kt + kg * 8, As + (size_t)tid * 8);
        }
        {   // stage B transposed: Bs[m][n], XOR-swizzled (n ^ ((m&3)<<3))
            int nl = tid & 31, m0 = (tid >> 5) * 8;
            int n = koff + kt + nl;
            const u16* src = P1n + ((size_t)b * 16384 + n) * 512 + h * 64 + m0;
            u16x4 p0 = *(const u16x4*)src;
            u16x4 p1 = *(const u16x4*)(src + 4);
            float ddv = DD[(size_t)bh * 16384 + n];
#pragma unroll
            for (int i = 0; i < 4; i++) {
                int m = m0 + i;
                Bs[m * 32 + (nl ^ ((m & 3) << 3))] = f2bf(bf2f(p0[i]) * ddv);
            }
#pragma unroll
            for (int i = 0; i < 4; i++) {
                int m = m0 + 4 + i;
                Bs[m * 32 + (nl ^ ((m & 3) << 3))] = f2bf(bf2f(p1[i]) * ddv);
            }
        }
        __syncthreads();
        bf16x8 af[2], bfv[2];
#pragma unroll
        for (int fm = 0; fm < 2; fm++)
            af[fm] = *(const bf16x8*)&As[(wr + fm * 16 + lrow) * 32 + lk];
#pragma unroll
        for (int fn = 0; fn < 2; fn++) {
            int m = wc + fn * 16 + lrow;
            bfv[fn] = *(const bf16x8*)&Bs[m * 32 + (lk ^ ((m & 3) << 3))];
        }
#pragma unroll
        for (int fm = 0; fm < 2; fm++)
#pragma unroll
            for (int fn = 0; fn < 2; fn++)
                acc[fm][fn] = __builtin_amdgcn_mfma_f32_16x16x32_bf16(
                    af[fm], bfv[fn], acc[fm][fn], 0, 0, 0);
    }
    float* C = latp + ((size_t)ch * 16 + bh) * 4096;
    int g = lane >> 4, li = lane & 15;
#pragma unroll
    for (int fm = 0; fm < 2; fm++)
#pragma unroll
        for (int fn = 0; fn < 2; fn++)
#pragma unroll
            for (int j = 0; j < 4; j++) {
                int row = wr + fm * 16 + g * 4 + j;   // d
                int col = wc + fn * 16 + li;          // m
                C[row * 64 + col] = acc[fm][fn][j];
            }
}

// finish latent: latB[bh][d][m] = w * (sum_ch latp)/den_enc[m]
__global__ void k_latfin(const float* latp, const float* dene, const float* smix,
                         u16* latB)
{
    int t = blockIdx.x * 256 + threadIdx.x;       // 16*64*64
    int bh = t >> 12, r = t & 4095;
    int m = r & 63;
    float w = 1.f / (1.f + __expf(-smix[0]));
    float s = 0.f;
    for (int c = 0; c < 16; c++) s += latp[((size_t)c * 16 + bh) * 4096 + r];
    int b = bh >> 3, h = bh & 7;
    float lat = s / dene[b * 512 + h * 64 + m];
    latB[(size_t)bh * 4096 + r] = f2bf(w * lat);
}

// ---------------------------------------------------------------------------
// k_om: OM[n][h*64+d] = sum_m P1n[n][h,m] * latB[bh][d][m] + OM2[n][h*64+d]
// ---------------------------------------------------------------------------
__global__ __launch_bounds__(256, 2) void k_om(const u16* P1n, const u16* latB,
                                               const u16* OM2, u16* OM)
{
    __shared__ u16 As[128 * 64], Bs2[64 * 64];
    int b = blockIdx.z, ntile = blockIdx.x;
    int tid = threadIdx.x, wid = tid >> 6, lane = tid & 63;
    int g = lane >> 4, li = lane & 15;
    int lrow = lane & 15, lk = g * 8;
    for (int h = 0; h < 8; h++) {
        __syncthreads();
#pragma unroll
        for (int i = 0; i < 4; i++) {     // stage A 128n x 64m swizzled
            int c = i * 256 + tid;
            int n = c >> 3, m0 = (c & 7) * 8;
            gload16(P1n + ((size_t)b * 16384 + ntile * 128 + n) * 512 + h * 64
                         + (m0 ^ ((n & 7) << 3)), As + (size_t)c * 8);
        }
#pragma unroll
        for (int i = 0; i < 2; i++) {     // stage B 64d x 64m swizzled
            int c = i * 256 + tid;
            int d = c >> 3, m0 = (c & 7) * 8;
            gload16(latB + (size_t)(b * 8 + h) * 4096 + d * 64
                         + (m0 ^ ((d & 7) << 3)), Bs2 + (size_t)c * 8);
        }
        __syncthreads();
        f32x4 oacc[2][4] = {};
#pragma unroll
        for (int kt = 0; kt < 64; kt += 32) {
            bf16x8 af[2], bfv[4];
#pragma unroll
            for (int fm = 0; fm < 2; fm++) {
                int r = wid * 32 + fm * 16 + lrow;
                af[fm] = *(const bf16x8*)&As[r * 64 + ((kt + lk) ^ ((r & 7) << 3))];
            }
#pragma unroll
            for (int fn = 0; fn < 4; fn++) {
                int d = fn * 16 + lrow;
                bfv[fn] = *(const bf16x8*)&Bs2[d * 64 + ((kt + lk) ^ ((d & 7) << 3))];
            }
#pragma unroll
            for (int fm = 0; fm < 2; fm++)
#pragma unroll
                for (int fn = 0; fn < 4; fn++)
                    oacc[fm][fn] = __builtin_amdgcn_mfma_f32_16x16x32_bf16(
                        af[fm], bfv[fn], oacc[fm][fn], 0, 0, 0);
        }
#pragma unroll
        for (int fm = 0; fm < 2; fm++)
#pragma unroll
            for (int fn = 0; fn < 4; fn++)
#pragma unroll
                for (int j = 0; j < 4; j++) {
                    int rl = wid * 32 + fm * 16 + g * 4 + j;
                    size_t addr = ((size_t)b * 16384 + ntile * 128 + rl) * 512
                                  + h * 64 + fn * 16 + li;
                    OM[addr] = f2bf(oacc[fm][fn][j] + bf2f(OM2[addr]));
                }
    }
}

// final: out(fp32) = OM @ Wo^T + bo.
__global__ __launch_bounds__(256, 2) void k_f(const u16* OM, const u16* wo16,
                                              const float* bo, float* out)
{
    __shared__ u16 As[128 * 32], Bs[128 * 32];
    f32x4 acc[4][4] = {};
    int f = blockIdx.y * gridDim.x + blockIdx.x;       // 1024 blocks
    int w = (f & 7) * 128 + (f >> 3);
    int tcol = (w & 3) * 128, trow = (w >> 2) * 128;
    gemm_core<128, 128, 2, 2>(OM, 512, MASK_NONE, 0, wo16, 512, MASK_NONE, 0,
                              512, trow, tcol, As, Bs, acc);
    int tid = threadIdx.x, wid = tid >> 6, lane = tid & 63;
    int wr = (wid & 1) * 64, wc = (wid >> 1) * 64;
    int g = lane >> 4, li = lane & 15;
#pragma unroll
    for (int fm = 0; fm < 4; fm++)
#pragma unroll
        for (int fn = 0; fn < 4; fn++) {
            int col = tcol + wc + fn * 16 + li;
            float bias = bo[col];
#pragma unroll
            for (int j = 0; j < 4; j++) {
                int row = trow + wr + fm * 16 + g * 4 + j;
                out[(size_t)row * 512 + col] = acc[fm][fn][j] + bias;
            }
        }
}

// ---------------------------------------------------------------------------
// Workspace layout (bytes), end ~147 MB (< proven-safe 209.7 MB).
// OM aliases XS (xs dead after k_Ldec/k_Lcross; k_om runs after).
// ---------------------------------------------------------------------------
static const size_t XS_OFF   = 0;            // u16 32768x512    (33,554,432)
static const size_t OMB_OFF  = 0;            // u16 32768x512    (alias XS)
static const size_t P1N_OFF  = 33554432;     // u16 2x16384x512  (33,554,432)
static const size_t OM2_OFF  = 67108864;     // u16 2x16384x512  (33,554,432)
static const size_t VT_OFF   = 100663296;    // u16 2x512x16384  (33,554,432)
static const size_t CKF_OFF  = 134217728;    // f32 512x512      (1,048,576)
static const size_t CQF_OFF  = 135266304;    // f32 512x512      (1,048,576)
static const size_t WV_OFF   = 136314880;    // u16 512x512      (524,288)
static const size_t WO_OFF   = 136839168;    // u16 512x512      (524,288)
static const size_t BIGB_OFF = 137363456;    // u16 2x1024x1024  (4,194,304)
static const size_t KCF_OFF  = 141557760;    // f32 16x64x64     (262,144)
static const size_t VCT_OFF  = 141819904;    // u16 16x64x64     (131,072)
static const size_t BKQ_OFF  = 141950976;    // f32 1024         (4,096)
static const size_t BV_OFF   = 141955072;    // f32 512          (2,048)
static const size_t CC_OFF   = 141957120;    // f32 2048         (8,192)
static const size_t DENP_OFF = 141965312;    // f32 1024x16      (65,536)
static const size_t DENE_OFF = 142030848;    // f32 1024         (4,096)
static const size_t DD_OFF   = 142034944;    // f32 16x16384     (1,048,576)
static const size_t LATP_OFF = 143083520;    // f32 16x16x64x64  (4,194,304)
static const size_t LATB_OFF = 147277824;    // u16 16x64x64     (131,072)
// end: 147,408,896

extern "C" void kernel_launch(void* const* d_in, const int* in_sizes, int n_in,
                              void* d_out, int out_size, void* d_ws, size_t ws_size,
                              hipStream_t stream)
{
    const float* x    = (const float*)d_in[0];
    const float* ctx  = (const float*)d_in[1];
    const float* qg   = (const float*)d_in[2];
    const float* Wx   = (const float*)d_in[3];
    const float* bx   = (const float*)d_in[4];
    const float* Wk   = (const float*)d_in[5];
    const float* bk   = (const float*)d_in[6];
    const float* Wv   = (const float*)d_in[7];
    const float* bv   = (const float*)d_in[8];
    const float* Wcq  = (const float*)d_in[9];
    const float* bcq  = (const float*)d_in[10];
    const float* Wck  = (const float*)d_in[11];
    const float* bck  = (const float*)d_in[12];
    const float* Wcv  = (const float*)d_in[13];
    const float* bcv  = (const float*)d_in[14];
    const float* smix = (const float*)d_in[15];
    const float* Wo   = (const float*)d_in[16];
    const float* bo   = (const float*)d_in[17];

    char* ws = (char*)d_ws;
    u16*   xs    = (u16*)  (ws + XS_OFF);
    u16*   OM    = (u16*)  (ws + OMB_OFF);
    u16*   P1n   = (u16*)  (ws + P1N_OFF);
    u16*   OM2   = (u16*)  (ws + OM2_OFF);
    u16*   vT    = (u16*)  (ws + VT_OFF);
    float* CKF   = (float*)(ws + CKF_OFF);
    float* CQF   = (float*)(ws + CQF_OFF);
    u16*   wV    = (u16*)  (ws + WV_OFF);
    u16*   wo16  = (u16*)  (ws + WO_OFF);
    u16*   BigB  = (u16*)  (ws + BIGB_OFF);
    float* kcf   = (float*)(ws + KCF_OFF);
    u16*   vcT   = (u16*)  (ws + VCT_OFF);
    float* biasKQ= (float*)(ws + BKQ_OFF);
    float* biasV = (float*)(ws + BV_OFF);
    float* CC    = (float*)(ws + CC_OFF);
    float* denp  = (float*)(ws + DENP_OFF);
    float* dene  = (float*)(ws + DENE_OFF);
    float* DD    = (float*)(ws + DD_OFF);
    float* latp  = (float*)(ws + LATP_OFF);
    u16*   latB  = (u16*)  (ws + LATB_OFF);

    prep_w   <<< 4096, 256, 0, stream>>>(Wk, Wcq, Wv, Wx, Wo, CKF, CQF, wV, wo16);
    prep_bias<<<    6, 256, 0, stream>>>(Wk, Wcq, Wv, bk, bcq, bv, bx, biasKQ, biasV);
    prep_ctx <<<  256, 256, 0, stream>>>(ctx, Wck, bck, Wcv, bcv, smix, kcf, vcT);
    prep_x   <<<16384, 256, 0, stream>>>(x, xs);
    prep_b2  <<< 3078, 256, 0, stream>>>(CKF, CQF, qg, kcf, biasKQ, BigB, CC);

    k_vt    <<<dim3(128,   4, 2), 256, 0, stream>>>(wV, xs, biasV, vT);
    k_Ldec  <<<1024, 256, 0, stream>>>(xs, BigB, CC, P1n, DD);
    k_Lcross<<<1024, 256, 0, stream>>>(xs, BigB, CC, vcT, OM2);
    k_dene  <<< 256, 256, 0, stream>>>(P1n, DD, denp);
    k_rden  <<<   4, 256, 0, stream>>>(denp, dene);
    k_latT  <<<dim3( 16,   1, 16), 256, 0, stream>>>(vT, P1n, DD, latp);
    k_latfin<<< 256, 256, 0, stream>>>(latp, dene, smix, latB);
    k_om    <<<dim3(128,   1, 2), 256, 0, stream>>>(P1n, latB, OM2, OM);
    k_f     <<<dim3(  4, 256, 1), 256, 0, stream>>>(OM, wo16, bo, (float*)d_out);
}

// Round 10
// 278.106 us; speedup vs baseline: 1.5119x; 1.4120x over previous
//
#include <hip/hip_runtime.h>

// ---------------------------------------------------------------------------
// GALE_FA: FLARE low-rank self-attn + context cross-attn + gated mix.
// R4: logits computed directly from x (k/q never materialized).
// R8: K-cut 1536->1024 (drop xl*Bhi), xs hi-only.
// R9: unified slim k_Lhalf (dec+cross share codegen); PV2 moved into k_om
// (OM = P1@latB + P2@vcS, two K=64 passes); vcS pre-swizzled in global.
// ---------------------------------------------------------------------------

typedef unsigned short u16;
typedef __attribute__((ext_vector_type(4))) float  f32x4;
typedef __attribute__((ext_vector_type(4))) u16    u16x4;
typedef __attribute__((ext_vector_type(8))) __bf16 bf16x8;

__device__ __forceinline__ float bf2f(u16 u) {
    return __uint_as_float(((unsigned)u) << 16);
}
__device__ __forceinline__ u16 f2bf(float f) {   // round-to-nearest-even
    unsigned u = __float_as_uint(f);
    u += 0x7fffu + ((u >> 16) & 1u);
    return (u16)(u >> 16);
}
__device__ __forceinline__ void gload16(const void* g, void* l) {
    __builtin_amdgcn_global_load_lds(
        (const __attribute__((address_space(1))) unsigned int*)g,
        (__attribute__((address_space(3))) unsigned int*)l, 16, 0, 0);
}

#define MASK_NONE 0x7fffffffu

// ---------------------------------------------------------------------------
// Generic MFMA GEMM core (m97-style 2-barrier loop, BK=32), 256 threads.
// ---------------------------------------------------------------------------
template<int BM, int BN, int WMW, int WNW>
__device__ __forceinline__ void gemm_core(
    const u16* __restrict__ A, int lda, unsigned amask, int koffA,
    const u16* __restrict__ Bm, int ldb, unsigned bmask, int koffB,
    int K, int trow, int tcol,
    u16* As, u16* Bs,
    f32x4 (&acc)[BM / WMW / 16][BN / WNW / 16])
{
    constexpr int FM = BM / WMW / 16;
    constexpr int FN = BN / WNW / 16;
    const int tid  = threadIdx.x;
    const int wid  = tid >> 6, lane = tid & 63;
    const int wm   = wid % WMW, wn = wid / WMW;
    const int wr   = wm * (BM / WMW), wc = wn * (BN / WNW);
    const int lrow = lane & 15, lk = (lane >> 4) * 8;

    for (int kt = 0; kt < K; kt += 32) {
        __syncthreads();
#pragma unroll
        for (int i = 0; i < BM / 64; i++) {           // stage A tile
            int c = i * 256 + tid;
            int row = c >> 2, kg = c & 3;
            unsigned kk = ((unsigned)(koffA + kt + kg * 8)) & amask;
            gload16(A + (size_t)(trow + row) * lda + kk, As + (size_t)c * 8);
        }
#pragma unroll
        for (int i = 0; i < BN / 64; i++) {           // stage B tile
            int c = i * 256 + tid;
            int col = c >> 2, kg = c & 3;
            unsigned kk = ((unsigned)(koffB + kt + kg * 8)) & bmask;
            gload16(Bm + (size_t)(tcol + col) * ldb + kk, Bs + (size_t)c * 8);
        }
        __syncthreads();

        bf16x8 af[FM], bfr[FN];
#pragma unroll
        for (int fm = 0; fm < FM; fm++)
            af[fm] = *(const bf16x8*)&As[(wr + fm * 16 + lrow) * 32 + lk];
#pragma unroll
        for (int fn = 0; fn < FN; fn++)
            bfr[fn] = *(const bf16x8*)&Bs[(wc + fn * 16 + lrow) * 32 + lk];
#pragma unroll
        for (int fm = 0; fm < FM; fm++)
#pragma unroll
            for (int fn = 0; fn < FN; fn++)
                acc[fm][fn] = __builtin_amdgcn_mfma_f32_16x16x32_bf16(
                    af[fm], bfr[fn], acc[fm][fn], 0, 0, 0);
    }
}

// ---------------------------------------------------------------------------
// Prep kernels (fp32 inputs)
// ---------------------------------------------------------------------------

// x -> xs = bf16(x) (hi only, row stride 512)
__global__ void prep_x(const float* __restrict__ x, u16* __restrict__ xs)
{
    int t = blockIdx.x * 256 + threadIdx.x;       // 2*16384*512/4
    int n = t >> 7, e4 = (t & 127) << 2;
    f32x4 v = *(const f32x4*)(x + (size_t)n * 512 + e4);
    u16x4 hi;
#pragma unroll
    for (int j = 0; j < 4; j++) hi[j] = f2bf(v[j]);
    *(u16x4*)(xs + (size_t)n * 512 + e4) = hi;
}

// which 0/1/2: CKF/CQF fp32, wV bf16 (composed with Wx); which 3: Wo -> bf16.
__global__ void prep_w(const float* Wk, const float* Wcq, const float* Wv,
                       const float* Wx, const float* Wo,
                       float* CKF, float* CQF, u16* wV, u16* wo16)
{
    int idx = blockIdx.x * 256 + threadIdx.x;     // 4*512*512
    int which = idx >> 18;
    int rem = idx & 262143;
    if (which == 3) { wo16[rem] = f2bf(Wo[rem]); return; }
    int c = rem >> 9, e = rem & 511;
    int h = c >> 6, d = c & 63;
    const float* W = which == 0 ? Wk : (which == 1 ? Wcq : Wv);
    float s = 0.f;
#pragma unroll 8
    for (int j = 0; j < 64; j++)
        s += W[d * 64 + j] * Wx[(h * 64 + j) * 512 + e];
    if (which == 0)      CKF[(size_t)c * 512 + e] = s;
    else if (which == 1) CQF[(size_t)c * 512 + e] = s;
    else                 wV [(size_t)c * 512 + e] = f2bf(s);
}

// Composed biases: biasKQ[0..511]=k-bias(h,d), [512..1023]=q-bias; biasV.
__global__ void prep_bias(const float* Wk, const float* Wcq, const float* Wv,
                          const float* bk, const float* bcq, const float* bv,
                          const float* bx, float* biasKQ, float* biasV)
{
    int t = blockIdx.x * 256 + threadIdx.x;       // 1536
    if (t < 1024) {
        const float* W  = (t < 512) ? Wk : Wcq;
        const float* bb = (t < 512) ? bk : bcq;
        int c = t & 511; int h = c >> 6, d = c & 63;
        float s = bb[d];
        for (int j = 0; j < 64; j++) s += W[d * 64 + j] * bx[h * 64 + j];
        biasKQ[t] = s;
    } else if (t < 1536) {
        int c = t - 1024; int h = c >> 6, d = c & 63;
        float s = bv[d];
        for (int j = 0; j < 64; j++) s += Wv[d * 64 + j] * bx[h * 64 + j];
        biasV[c] = s;
    }
}

// context: kc fp32 [bh][s][d]; vcS bf16 [bh][d][s-swizzled], pre-scaled by
// (1-sigmoid(smix)).  Swizzle baked into GLOBAL layout so k_om's
// global_load_lds (linear src+dest) lands the swizzled LDS layout directly.
__global__ void prep_ctx(const float* ctx, const float* Wck, const float* bck,
                         const float* Wcv, const float* bcv, const float* smix,
                         float* kcf, u16* vcS)
{
    int t = blockIdx.x * 256 + threadIdx.x;       // 16*64*64
    int bh = t >> 12, r = t & 4095;
    int s_ = r >> 6, d = r & 63;
    const float* crow = ctx + ((size_t)bh * 64 + s_) * 64;
    float kc = bck[d], vc = bcv[d];
#pragma unroll 8
    for (int e = 0; e < 64; e++) {
        float ce = crow[e];
        kc += ce * Wck[d * 64 + e];
        vc += ce * Wcv[d * 64 + e];
    }
    kcf[(size_t)bh * 4096 + s_ * 64 + d] = kc;
    float w = 1.f / (1.f + __expf(-smix[0]));
    vcS[(size_t)bh * 4096 + d * 64 + (s_ ^ ((d & 7) << 3))] = f2bf((1.f - w) * vc);
}

// Merged: kg rows (BigB 0..511 [lo|hi], both b), kq rows (512+hs), CC consts.
__global__ void prep_b2(const float* CKF, const float* CQF, const float* qg,
                        const float* kcf, const float* biasKQ, u16* BigB, float* CC)
{
    int idx = blockIdx.x * 256 + threadIdx.x;     // 262144 + 524288 + 1536
    if (idx < 262144) {
        int hm = idx >> 9, e = idx & 511;
        int h = hm >> 6;
        float s = 0.f;
#pragma unroll 8
        for (int d = 0; d < 64; d++)
            s += CKF[(size_t)(h * 64 + d) * 512 + e] * qg[(size_t)hm * 64 + d];
        u16 hi = f2bf(s), lo = f2bf(s - bf2f(hi));
#pragma unroll
        for (int b = 0; b < 2; b++) {
            size_t base = (size_t)b * 1048576 + (size_t)hm * 1024;
            BigB[base + e]       = lo;
            BigB[base + 512 + e] = hi;
        }
    } else if (idx < 786432) {
        int i2 = idx - 262144;
        int r = i2 >> 9, e = i2 & 511;
        int b = r >> 9, hs = r & 511;
        int h = hs >> 6, s_ = hs & 63;
        float s = 0.f;
#pragma unroll 8
        for (int d = 0; d < 64; d++)
            s += CQF[(size_t)(h * 64 + d) * 512 + e]
               * kcf[(size_t)(b * 8 + h) * 4096 + s_ * 64 + d];
        u16 hi = f2bf(s), lo = f2bf(s - bf2f(hi));
        size_t base = (size_t)b * 1048576 + (size_t)(512 + hs) * 1024;
        BigB[base + e]       = lo;
        BigB[base + 512 + e] = hi;
    } else if (idx < 787968) {
        int t = idx - 786432;                     // 0..1535
        if (t < 512) {
            int h = t >> 6;
            float s = 0.f;
            for (int d = 0; d < 64; d++) s += biasKQ[h * 64 + d] * qg[(size_t)t * 64 + d];
            CC[t] = s; CC[1024 + t] = s;
        } else {
            int j = t - 512;
            int b = j >> 9, hs = j & 511;
            int h = hs >> 6, s_ = hs & 63;
            float s = 0.f;
            for (int d = 0; d < 64; d++)
                s += biasKQ[512 + h * 64 + d]
                   * kcf[(size_t)(b * 8 + h) * 4096 + s_ * 64 + d];
            CC[b * 1024 + 512 + hs] = s;
        }
    }
}

// vT = CV @ xs^T (+row bias): vT[b][hd][n]
__global__ __launch_bounds__(256, 2) void k_vt(const u16* wV, const u16* xs,
                                               const float* biasV, u16* vT)
{
    __shared__ u16 As[128 * 32], Bs[128 * 32];
    f32x4 acc[4][4] = {};
    int b = blockIdx.z;
    int f = blockIdx.y * gridDim.x + blockIdx.x;       // 512 blocks per z
    int w = (f & 7) * 64 + (f >> 3);
    int trow = (w & 3) * 128;
    int tcol = (w >> 2) * 128;
    gemm_core<128, 128, 2, 2>(wV, 512, MASK_NONE, 0,
                              xs + (size_t)b * 8388608, 512, MASK_NONE, 0,
                              512, trow, tcol, As, Bs, acc);
    int tid = threadIdx.x, wid = tid >> 6, lane = tid & 63;
    int wr = (wid & 1) * 64, wc = (wid >> 1) * 64;
    int g = lane >> 4, li = lane & 15;
#pragma unroll
    for (int fm = 0; fm < 4; fm++)
#pragma unroll
        for (int fn = 0; fn < 4; fn++) {
            int col = tcol + wc + fn * 16 + li;
#pragma unroll
            for (int j = 0; j < 4; j++) {
                int a = trow + wr + fm * 16 + g * 4 + j;
                vT[((size_t)b * 512 + a) * 16384 + col] = f2bf(acc[fm][fn][j] + biasV[a]);
            }
        }
}

// ---------------------------------------------------------------------------
// k_Lhalf: one 512-col half of the logit matrix. 128n x 128(h,m|h,s) per
// block, K=1024.  E=exp(L+c); softmax over the 64-col head group (in-wave)
// -> Pout; if DD != null also store the un-normalized row-sum (dec half).
// Launched twice: (colbase=0, Pout=P1n, DD) and (colbase=512, Pout=P2n, 0).
// ---------------------------------------------------------------------------
__global__ void k_Lhalf(const u16* xs, const u16* BigB, const float* CC,
                        int colbase, u16* Pout, float* DD)
{
    __shared__ u16 As[128 * 32], Bs[128 * 32];
    f32x4 acc[4][4] = {};
    int f = blockIdx.x;                  // 1024
    int w = (f & 7) * 128 + (f >> 3);    // XCD-chunked, bijective
    int jt = w & 3, nb = w >> 2;
    int b = nb >> 7, ntile = nb & 127;
    int trow = ntile * 128, tcol = colbase + jt * 128;
    gemm_core<128, 128, 2, 2>(xs + (size_t)b * 8388608, 512, 511u, 0,
                              BigB + (size_t)b * 1048576, 1024, MASK_NONE, 0,
                              1024, trow, tcol, As, Bs, acc);
    int tid = threadIdx.x, wid = tid >> 6, lane = tid & 63;
    int wm = wid & 1, wn = wid >> 1;
    int wr = wm * 64, wc = wn * 64;
    int g = lane >> 4, li = lane & 15;
    float cj[4];
#pragma unroll
    for (int fn = 0; fn < 4; fn++) cj[fn] = CC[b * 1024 + tcol + wc + fn * 16 + li];

    int h = jt * 2 + wn;                 // head within this half
#pragma unroll
    for (int fm = 0; fm < 4; fm++)
#pragma unroll
        for (int j = 0; j < 4; j++) {
            float ev[4]; float dsum = 0.f;
#pragma unroll
            for (int fn = 0; fn < 4; fn++) {
                ev[fn] = __expf(acc[fm][fn][j] + cj[fn]);
                dsum += ev[fn];
            }
            dsum += __shfl_xor(dsum, 1); dsum += __shfl_xor(dsum, 2);
            dsum += __shfl_xor(dsum, 4); dsum += __shfl_xor(dsum, 8);
            float inv = 1.f / dsum;
            int row = trow + wr + fm * 16 + g * 4 + j;
            size_t pb = ((size_t)b * 16384 + row) * 512 + h * 64;
#pragma unroll
            for (int fn = 0; fn < 4; fn++)
                Pout[pb + fn * 16 + li] = f2bf(ev[fn] * inv);
            if (DD != nullptr && li == 0)
                DD[(size_t)(b * 8 + h) * 16384 + row] = dsum;
        }
}

// ---------------------------------------------------------------------------
// k_dene: den_enc partials from P1n*DD: denp[(b,h,m)][c] = sum_{n in chunk c} E
// ---------------------------------------------------------------------------
__global__ void k_dene(const u16* P1n, const float* DD, float* denp)
{
    __shared__ float denL[4][64];
    int blk = blockIdx.x;                 // 256 = bh*16 + c
    int bh = blk >> 4, c = blk & 15;
    int b = bh >> 3, h = bh & 7;
    int t = threadIdx.x;
    int m = t & 63, r = (t >> 6) & 3;
    float s = 0.f;
    const u16* base = P1n + (size_t)b * 16384 * 512 + h * 64 + m;
    const float* ddb = DD + (size_t)bh * 16384;
    for (int i = 0; i < 256; i++) {
        int n = c * 1024 + i * 4 + r;
        s += bf2f(base[(size_t)n * 512]) * ddb[n];
    }
    denL[r][m] = s;
    __syncthreads();
    if (t < 64)
        denp[(size_t)(b * 512 + h * 64 + t) * 16 + c]
            = denL[0][t] + denL[1][t] + denL[2][t] + denL[3][t];
}

__global__ void k_rden(const float* denp, float* dene)
{
    int t = blockIdx.x * 256 + threadIdx.x;       // 1024
    if (t < 1024) {
        float s = 0.f;
        const float* p = denp + (size_t)t * 16;
        for (int i = 0; i < 16; i++) s += p[i];
        dene[t] = s;
    }
}

// ---------------------------------------------------------------------------
// latT: latp[ch][bh][d][m] = sum_n vT[d][n] * (P1n[n][h,m]*DD[n])  (split-K 16)
// ---------------------------------------------------------------------------
__global__ __launch_bounds__(256, 2) void k_latT(const u16* vT, const u16* P1n,
                                                 const float* DD, float* latp)
{
    __shared__ u16 As[64 * 32], Bs[64 * 32];
    f32x4 acc[2][2] = {};
    int ch = blockIdx.x, bh = blockIdx.z;
    int b = bh >> 3, h = bh & 7;
    int koff = ch * 1024;
    int tid = threadIdx.x, wid = tid >> 6, lane = tid & 63;
    int wr = (wid & 1) * 32, wc = (wid >> 1) * 32;
    int lrow = lane & 15, lk = (lane >> 4) * 8;
    const u16* Avt = vT + (size_t)bh * 64 * 16384;

    for (int kt = 0; kt < 1024; kt += 32) {
        __syncthreads();
        {   // stage A: vT rows 64 x 32k
            int row = tid >> 2, kg = tid & 3;
            gload16(Avt + (size_t)row * 16384 + koff + kt + kg * 8, As + (size_t)tid * 8);
        }
        {   // stage B transposed: Bs[m][n], XOR-swizzled (n ^ ((m&3)<<3))
            int nl = tid & 31, m0 = (tid >> 5) * 8;
            int n = koff + kt + nl;
            const u16* src = P1n + ((size_t)b * 16384 + n) * 512 + h * 64 + m0;
            u16x4 p0 = *(const u16x4*)src;
            u16x4 p1 = *(const u16x4*)(src + 4);
            float ddv = DD[(size_t)bh * 16384 + n];
#pragma unroll
            for (int i = 0; i < 4; i++) {
                int m = m0 + i;
                Bs[m * 32 + (nl ^ ((m & 3) << 3))] = f2bf(bf2f(p0[i]) * ddv);
            }
#pragma unroll
            for (int i = 0; i < 4; i++) {
                int m = m0 + 4 + i;
                Bs[m * 32 + (nl ^ ((m & 3) << 3))] = f2bf(bf2f(p1[i]) * ddv);
            }
        }
        __syncthreads();
        bf16x8 af[2], bfv[2];
#pragma unroll
        for (int fm = 0; fm < 2; fm++)
            af[fm] = *(const bf16x8*)&As[(wr + fm * 16 + lrow) * 32 + lk];
#pragma unroll
        for (int fn = 0; fn < 2; fn++) {
            int m = wc + fn * 16 + lrow;
            bfv[fn] = *(const bf16x8*)&Bs[m * 32 + (lk ^ ((m & 3) << 3))];
        }
#pragma unroll
        for (int fm = 0; fm < 2; fm++)
#pragma unroll
            for (int fn = 0; fn < 2; fn++)
                acc[fm][fn] = __builtin_amdgcn_mfma_f32_16x16x32_bf16(
                    af[fm], bfv[fn], acc[fm][fn], 0, 0, 0);
    }
    float* C = latp + ((size_t)ch * 16 + bh) * 4096;
    int g = lane >> 4, li = lane & 15;
#pragma unroll
    for (int fm = 0; fm < 2; fm++)
#pragma unroll
        for (int fn = 0; fn < 2; fn++)
#pragma unroll
            for (int j = 0; j < 4; j++) {
                int row = wr + fm * 16 + g * 4 + j;   // d
                int col = wc + fn * 16 + li;          // m
                C[row * 64 + col] = acc[fm][fn][j];
            }
}

// finish latent: latB[bh][d][m] = w * (sum_ch latp)/den_enc[m]
__global__ void k_latfin(const float* latp, const float* dene, const float* smix,
                         u16* latB)
{
    int t = blockIdx.x * 256 + threadIdx.x;       // 16*64*64
    int bh = t >> 12, r = t & 4095;
    int m = r & 63;
    float w = 1.f / (1.f + __expf(-smix[0]));
    float s = 0.f;
    for (int c = 0; c < 16; c++) s += latp[((size_t)c * 16 + bh) * 4096 + r];
    int b = bh >> 3, h = bh & 7;
    float lat = s / dene[b * 512 + h * 64 + m];
    latB[(size_t)bh * 4096 + r] = f2bf(w * lat);
}

// ---------------------------------------------------------------------------
// k_om: OM[n][h*64+d] = sum_m P1n[n][h,m]*latB[bh][d][m]
//                     + sum_s P2n[n][h,s]*vcS[bh][d][s]   (two K=64 passes)
// ---------------------------------------------------------------------------
__global__ __launch_bounds__(256, 2) void k_om(const u16* P1n, const u16* P2n,
                                               const u16* latB, const u16* vcS,
                                               u16* OM)
{
    __shared__ u16 As1[128 * 64], As2[128 * 64], Bs1[64 * 64], Vs[64 * 64];
    int b = blockIdx.z, ntile = blockIdx.x;
    int tid = threadIdx.x, wid = tid >> 6, lane = tid & 63;
    int g = lane >> 4, li = lane & 15;
    int lrow = lane & 15, lk = g * 8;
    for (int h = 0; h < 8; h++) {
        __syncthreads();
#pragma unroll
        for (int i = 0; i < 4; i++) {     // stage A1/A2: 128n x 64 swizzled
            int c = i * 256 + tid;
            int n = c >> 3, m0 = (c & 7) * 8;
            size_t srcoff = ((size_t)b * 16384 + ntile * 128 + n) * 512 + h * 64
                          + (m0 ^ ((n & 7) << 3));
            gload16(P1n + srcoff, As1 + (size_t)c * 8);
            gload16(P2n + srcoff, As2 + (size_t)c * 8);
        }
#pragma unroll
        for (int i = 0; i < 2; i++) {     // stage B1 (latB, inv-swz src) + Vs (pre-swz)
            int c = i * 256 + tid;
            int d = c >> 3, m0 = (c & 7) * 8;
            gload16(latB + (size_t)(b * 8 + h) * 4096 + d * 64
                         + (m0 ^ ((d & 7) << 3)), Bs1 + (size_t)c * 8);
            gload16(vcS  + (size_t)(b * 8 + h) * 4096 + d * 64 + m0,
                    Vs + (size_t)c * 8);
        }
        __syncthreads();
        f32x4 oacc[2][4] = {};
#pragma unroll
        for (int kt = 0; kt < 64; kt += 32) {
            bf16x8 af[2], bfv[4];
#pragma unroll
            for (int fm = 0; fm < 2; fm++) {
                int r = wid * 32 + fm * 16 + lrow;
                af[fm] = *(const bf16x8*)&As1[r * 64 + ((kt + lk) ^ ((r & 7) << 3))];
            }
#pragma unroll
            for (int fn = 0; fn < 4; fn++) {
                int d = fn * 16 + lrow;
                bfv[fn] = *(const bf16x8*)&Bs1[d * 64 + ((kt + lk) ^ ((d & 7) << 3))];
            }
#pragma unroll
            for (int fm = 0; fm < 2; fm++)
#pragma unroll
                for (int fn = 0; fn < 4; fn++)
                    oacc[fm][fn] = __builtin_amdgcn_mfma_f32_16x16x32_bf16(
                        af[fm], bfv[fn], oacc[fm][fn], 0, 0, 0);
#pragma unroll
            for (int fm = 0; fm < 2; fm++) {
                int r = wid * 32 + fm * 16 + lrow;
                af[fm] = *(const bf16x8*)&As2[r * 64 + ((kt + lk) ^ ((r & 7) << 3))];
            }
#pragma unroll
            for (int fn = 0; fn < 4; fn++) {
                int d = fn * 16 + lrow;
                bfv[fn] = *(const bf16x8*)&Vs[d * 64 + ((kt + lk) ^ ((d & 7) << 3))];
            }
#pragma unroll
            for (int fm = 0; fm < 2; fm++)
#pragma unroll
                for (int fn = 0; fn < 4; fn++)
                    oacc[fm][fn] = __builtin_amdgcn_mfma_f32_16x16x32_bf16(
                        af[fm], bfv[fn], oacc[fm][fn], 0, 0, 0);
        }
#pragma unroll
        for (int fm = 0; fm < 2; fm++)
#pragma unroll
            for (int fn = 0; fn < 4; fn++)
#pragma unroll
                for (int j = 0; j < 4; j++) {
                    int rl = wid * 32 + fm * 16 + g * 4 + j;
                    size_t addr = ((size_t)b * 16384 + ntile * 128 + rl) * 512
                                  + h * 64 + fn * 16 + li;
                    OM[addr] = f2bf(oacc[fm][fn][j]);
                }
    }
}

// final: out(fp32) = OM @ Wo^T + bo.
__global__ __launch_bounds__(256, 2) void k_f(const u16* OM, const u16* wo16,
                                              const float* bo, float* out)
{
    __shared__ u16 As[128 * 32], Bs[128 * 32];
    f32x4 acc[4][4] = {};
    int f = blockIdx.y * gridDim.x + blockIdx.x;       // 1024 blocks
    int w = (f & 7) * 128 + (f >> 3);
    int tcol = (w & 3) * 128, trow = (w >> 2) * 128;
    gemm_core<128, 128, 2, 2>(OM, 512, MASK_NONE, 0, wo16, 512, MASK_NONE, 0,
                              512, trow, tcol, As, Bs, acc);
    int tid = threadIdx.x, wid = tid >> 6, lane = tid & 63;
    int wr = (wid & 1) * 64, wc = (wid >> 1) * 64;
    int g = lane >> 4, li = lane & 15;
#pragma unroll
    for (int fm = 0; fm < 4; fm++)
#pragma unroll
        for (int fn = 0; fn < 4; fn++) {
            int col = tcol + wc + fn * 16 + li;
            float bias = bo[col];
#pragma unroll
            for (int j = 0; j < 4; j++) {
                int row = trow + wr + fm * 16 + g * 4 + j;
                out[(size_t)row * 512 + col] = acc[fm][fn][j] + bias;
            }
        }
}

// ---------------------------------------------------------------------------
// Workspace layout (bytes), end ~147 MB (< proven-safe 209.7 MB).
// OM aliases XS (xs dead after both k_Lhalf launches; k_om runs after).
// ---------------------------------------------------------------------------
static const size_t XS_OFF   = 0;            // u16 32768x512    (33,554,432)
static const size_t OMB_OFF  = 0;            // u16 32768x512    (alias XS)
static const size_t P1N_OFF  = 33554432;     // u16 2x16384x512  (33,554,432)
static const size_t P2N_OFF  = 67108864;     // u16 2x16384x512  (33,554,432)
static const size_t VT_OFF   = 100663296;    // u16 2x512x16384  (33,554,432)
static const size_t CKF_OFF  = 134217728;    // f32 512x512      (1,048,576)
static const size_t CQF_OFF  = 135266304;    // f32 512x512      (1,048,576)
static const size_t WV_OFF   = 136314880;    // u16 512x512      (524,288)
static const size_t WO_OFF   = 136839168;    // u16 512x512      (524,288)
static const size_t BIGB_OFF = 137363456;    // u16 2x1024x1024  (4,194,304)
static const size_t KCF_OFF  = 141557760;    // f32 16x64x64     (262,144)
static const size_t VCS_OFF  = 141819904;    // u16 16x64x64     (131,072)
static const size_t BKQ_OFF  = 141950976;    // f32 1024         (4,096)
static const size_t BV_OFF   = 141955072;    // f32 512          (2,048)
static const size_t CC_OFF   = 141957120;    // f32 2048         (8,192)
static const size_t DENP_OFF = 141965312;    // f32 1024x16      (65,536)
static const size_t DENE_OFF = 142030848;    // f32 1024         (4,096)
static const size_t DD_OFF   = 142034944;    // f32 16x16384     (1,048,576)
static const size_t LATP_OFF = 143083520;    // f32 16x16x64x64  (4,194,304)
static const size_t LATB_OFF = 147277824;    // u16 16x64x64     (131,072)
// end: 147,408,896

extern "C" void kernel_launch(void* const* d_in, const int* in_sizes, int n_in,
                              void* d_out, int out_size, void* d_ws, size_t ws_size,
                              hipStream_t stream)
{
    const float* x    = (const float*)d_in[0];
    const float* ctx  = (const float*)d_in[1];
    const float* qg   = (const float*)d_in[2];
    const float* Wx   = (const float*)d_in[3];
    const float* bx   = (const float*)d_in[4];
    const float* Wk   = (const float*)d_in[5];
    const float* bk   = (const float*)d_in[6];
    const float* Wv   = (const float*)d_in[7];
    const float* bv   = (const float*)d_in[8];
    const float* Wcq  = (const float*)d_in[9];
    const float* bcq  = (const float*)d_in[10];
    const float* Wck  = (const float*)d_in[11];
    const float* bck  = (const float*)d_in[12];
    const float* Wcv  = (const float*)d_in[13];
    const float* bcv  = (const float*)d_in[14];
    const float* smix = (const float*)d_in[15];
    const float* Wo   = (const float*)d_in[16];
    const float* bo   = (const float*)d_in[17];

    char* ws = (char*)d_ws;
    u16*   xs    = (u16*)  (ws + XS_OFF);
    u16*   OM    = (u16*)  (ws + OMB_OFF);
    u16*   P1n   = (u16*)  (ws + P1N_OFF);
    u16*   P2n   = (u16*)  (ws + P2N_OFF);
    u16*   vT    = (u16*)  (ws + VT_OFF);
    float* CKF   = (float*)(ws + CKF_OFF);
    float* CQF   = (float*)(ws + CQF_OFF);
    u16*   wV    = (u16*)  (ws + WV_OFF);
    u16*   wo16  = (u16*)  (ws + WO_OFF);
    u16*   BigB  = (u16*)  (ws + BIGB_OFF);
    float* kcf   = (float*)(ws + KCF_OFF);
    u16*   vcS   = (u16*)  (ws + VCS_OFF);
    float* biasKQ= (float*)(ws + BKQ_OFF);
    float* biasV = (float*)(ws + BV_OFF);
    float* CC    = (float*)(ws + CC_OFF);
    float* denp  = (float*)(ws + DENP_OFF);
    float* dene  = (float*)(ws + DENE_OFF);
    float* DD    = (float*)(ws + DD_OFF);
    float* latp  = (float*)(ws + LATP_OFF);
    u16*   latB  = (u16*)  (ws + LATB_OFF);

    prep_w   <<< 4096, 256, 0, stream>>>(Wk, Wcq, Wv, Wx, Wo, CKF, CQF, wV, wo16);
    prep_bias<<<    6, 256, 0, stream>>>(Wk, Wcq, Wv, bk, bcq, bv, bx, biasKQ, biasV);
    prep_ctx <<<  256, 256, 0, stream>>>(ctx, Wck, bck, Wcv, bcv, smix, kcf, vcS);
    prep_x   <<<16384, 256, 0, stream>>>(x, xs);
    prep_b2  <<< 3078, 256, 0, stream>>>(CKF, CQF, qg, kcf, biasKQ, BigB, CC);

    k_vt    <<<dim3(128,   4, 2), 256, 0, stream>>>(wV, xs, biasV, vT);
    k_Lhalf <<<1024, 256, 0, stream>>>(xs, BigB, CC, 0,   P1n, DD);
    k_Lhalf <<<1024, 256, 0, stream>>>(xs, BigB, CC, 512, P2n, (float*)nullptr);
    k_dene  <<< 256, 256, 0, stream>>>(P1n, DD, denp);
    k_rden  <<<   4, 256, 0, stream>>>(denp, dene);
    k_latT  <<<dim3( 16,   1, 16), 256, 0, stream>>>(vT, P1n, DD, latp);
    k_latfin<<< 256, 256, 0, stream>>>(latp, dene, smix, latB);
    k_om    <<<dim3(128,   1, 2), 256, 0, stream>>>(P1n, P2n, latB, vcS, OM);
    k_f     <<<dim3(  4, 256, 1), 256, 0, stream>>>(OM, wo16, bo, (float*)d_out);
}